// Round 15
// baseline (801.334 us; speedup 1.0000x reference)
//
#include <hip/hip_runtime.h>
#include <hip/hip_bf16.h>
#include <math.h>

typedef __attribute__((ext_vector_type(4))) float f32x4;
typedef __attribute__((ext_vector_type(8))) short bf16x8;

static constexpr int B_   = 2;
static constexpr int DM_  = 256;
static constexpr int NL_  = 2;
static constexpr int LEN_ = 18720;
static constexpr int NQ_  = 37440;           // B*LEN
static constexpr int NQP_ = 37504;           // 128*293

__device__ __forceinline__ unsigned short f2bf(float x) {
    __hip_bfloat16 h = __float2bfloat16(x);
    return *reinterpret_cast<unsigned short*>(&h);
}

// ============ flatten: all levels in one kernel; emits src f32/bf16, pos, qbf ===
struct FlatArgs { const float* s[4]; const float* p[4]; };
__global__ __launch_bounds__(256) void k_flatten(FlatArgs a, const float* __restrict__ lemb,
                                                 float* __restrict__ src,
                                                 unsigned short* __restrict__ srcbf,
                                                 float* __restrict__ pos,
                                                 unsigned short* __restrict__ qbf) {
    int t = blockIdx.x, c = threadIdx.x;
    int l, rel;
    if (t < 32768)      { l = 0; rel = t; }
    else if (t < 36864) { l = 1; rel = t - 32768; }
    else if (t < 37376) { l = 2; rel = t - 36864; }
    else                { l = 3; rel = t - 37376; }
    const int SH[4] = {14, 11, 8, 5};            // log2(S)
    const int OFF[4] = {0, 16384, 18432, 18688};
    int S = 1 << SH[l];
    int b = rel >> SH[l], s = rel & (S - 1);
    float sv = a.s[l][(size_t)(b * DM_ + c) * S + s];
    float pv = a.p[l][(size_t)(b * DM_ + c) * S + s] + lemb[l * DM_ + c];
    size_t row = (size_t)b * LEN_ + OFF[l] + s;
    src[row * DM_ + c] = sv;
    srcbf[row * DM_ + c] = f2bf(sv);
    pos[row * DM_ + c] = pv;
    qbf[row * DM_ + c] = f2bf(sv + pv);
}

// ============ weight prep: all transposes in one kernel ============
struct WPEnt { const float* s; unsigned short* d; int K, N, start; };
struct WPArgs { WPEnt e[12]; };
__global__ __launch_bounds__(256) void k_wprep_all(WPArgs a) {
    __shared__ float t[32][33];
    int bidx = blockIdx.x;
    int i = 0;
#pragma unroll
    for (int j = 1; j < 12; ++j) if (bidx >= a.e[j].start) i = j;
    const float* W = a.e[i].s;
    unsigned short* Wt = a.e[i].d;
    int K = a.e[i].K, N = a.e[i].N;
    int ti = bidx - a.e[i].start;
    int tilesX = N >> 5;
    int bx = ti % tilesX, by = ti / tilesX;
    int n0 = bx * 32, k0 = by * 32;
    int tx = threadIdx.x & 31, ty = threadIdx.x >> 5;
#pragma unroll
    for (int q = 0; q < 4; ++q)
        t[ty + q * 8][tx] = W[(size_t)(k0 + ty + q * 8) * N + n0 + tx];
    __syncthreads();
#pragma unroll
    for (int q = 0; q < 4; ++q)
        Wt[(size_t)(n0 + ty + q * 8) * K + k0 + tx] = f2bf(t[tx][ty + q * 8]);
}

// ============ bf16 MFMA GEMM, 128x128 tile, BK=32 ============
// MODE 0: C fp32.  MODE 1: relu -> Cbf bf16.  MODE 2: Cbf bf16.
template<int K, int MODE>
__global__ __launch_bounds__(256) void k_gemm(const unsigned short* __restrict__ A,
                                              const unsigned short* __restrict__ Bt,
                                              const float* __restrict__ bias,
                                              const float* __restrict__ bias2,
                                              int nsplit,
                                              float* __restrict__ C,
                                              unsigned short* __restrict__ Cbf,
                                              int N) {
    __shared__ unsigned short As[128 * 32];
    __shared__ unsigned short Bs[128 * 32];
    int tid = threadIdx.x;
    int w = tid >> 6, lane = tid & 63;
    int wr = w >> 1, wc = w & 1;
    int row0 = blockIdx.x * 128, col0 = blockIdx.y * 128;

    const unsigned short* gA = A + (size_t)(row0 + w * 32 + (lane >> 2)) * K + (lane & 3) * 8;
    const unsigned short* gB = Bt + (size_t)(col0 + w * 32 + (lane >> 2)) * K + (lane & 3) * 8;
    char* lA0 = (char*)As + w * 2048;
    char* lB0 = (char*)Bs + w * 2048;

    f32x4 acc[4][4];
#pragma unroll
    for (int m = 0; m < 4; ++m)
#pragma unroll
        for (int n = 0; n < 4; ++n) acc[m][n] = (f32x4){0.f, 0.f, 0.f, 0.f};

    int lr = lane & 15, lk = (lane >> 4) * 8;
    const unsigned short* pA = &As[(wr * 64 + lr) * 32 + lk];
    const unsigned short* pB = &Bs[(wc * 64 + lr) * 32 + lk];

    for (int kt = 0; kt < K; kt += 32) {
        __builtin_amdgcn_global_load_lds((const __attribute__((address_space(1))) void*)gA,
                                         (__attribute__((address_space(3))) void*)lA0, 16, 0, 0);
        __builtin_amdgcn_global_load_lds((const __attribute__((address_space(1))) void*)(gA + (size_t)16 * K),
                                         (__attribute__((address_space(3))) void*)(lA0 + 1024), 16, 0, 0);
        __builtin_amdgcn_global_load_lds((const __attribute__((address_space(1))) void*)gB,
                                         (__attribute__((address_space(3))) void*)lB0, 16, 0, 0);
        __builtin_amdgcn_global_load_lds((const __attribute__((address_space(1))) void*)(gB + (size_t)16 * K),
                                         (__attribute__((address_space(3))) void*)(lB0 + 1024), 16, 0, 0);
        gA += 32; gB += 32;
        __syncthreads();
        bf16x8 a[4], b[4];
#pragma unroll
        for (int m = 0; m < 4; ++m) a[m] = *(const bf16x8*)(pA + m * 16 * 32);
#pragma unroll
        for (int n = 0; n < 4; ++n) b[n] = *(const bf16x8*)(pB + n * 16 * 32);
#pragma unroll
        for (int m = 0; m < 4; ++m)
#pragma unroll
            for (int n = 0; n < 4; ++n)
                acc[m][n] = __builtin_amdgcn_mfma_f32_16x16x32_bf16(a[m], b[n], acc[m][n], 0, 0, 0);
        __syncthreads();
    }

    int fr = (lane >> 4) * 4, fc = lane & 15;
#pragma unroll
    for (int m = 0; m < 4; ++m) {
#pragma unroll
        for (int n = 0; n < 4; ++n) {
            int cc = col0 + wc * 64 + n * 16 + fc;
            float bv = (cc < nsplit) ? bias[cc] : bias2[cc - nsplit];
#pragma unroll
            for (int i = 0; i < 4; ++i) {
                int cr = row0 + wr * 64 + m * 16 + fr + i;
                float v = acc[m][n][i] + bv;
                if (MODE == 1) {
                    Cbf[(size_t)cr * N + cc] = f2bf(fmaxf(v, 0.f));
                } else if (MODE == 2) {
                    Cbf[(size_t)cr * N + cc] = f2bf(v);
                } else {
                    C[(size_t)cr * N + cc] = v;
                }
            }
        }
    }
}

// ============ fused GEMM(N=256) + bias + residual + LayerNorm (v2) ===========
// O = LN(X + A@Bt^T + bias); Obf = bf16(O); optional qbf = bf16(O + pos).
// BM=64, BN=256 (full row in block), BK=32; 4 waves 2x2; wave tile 32x128.
// Grid = NQP/64 = 586 blocks. acc[2][8] = 64 f32/lane.
template<int K>
__global__ __launch_bounds__(256) void k_gemm_ln(const unsigned short* __restrict__ A,
                                                 const unsigned short* __restrict__ Bt,
                                                 const float* __restrict__ bias,
                                                 const float* __restrict__ X,
                                                 const float* __restrict__ g,
                                                 const float* __restrict__ bb,
                                                 float* __restrict__ O,
                                                 unsigned short* __restrict__ Obf,
                                                 const float* __restrict__ pos,
                                                 unsigned short* __restrict__ qbf) {
    __shared__ unsigned short As[64 * 32];     // 4 KB
    __shared__ unsigned short Bs[256 * 32];    // 16 KB
    __shared__ float red[2][2][64];            // 2 KB
    int tid = threadIdx.x;
    int w = tid >> 6, lane = tid & 63;
    int wr = w >> 1, wc = w & 1;
    int row0 = blockIdx.x * 64;

    // staging: wave w stages 16 rows of A and 64 rows of Bt
    const unsigned short* gA = A + (size_t)(row0 + w * 16 + (lane >> 2)) * K + (lane & 3) * 8;
    const unsigned short* gB = Bt + (size_t)(w * 64 + (lane >> 2)) * K + (lane & 3) * 8;
    char* lA0 = (char*)As + w * 1024;
    char* lB0 = (char*)Bs + w * 4096;

    f32x4 acc[2][8];
#pragma unroll
    for (int m = 0; m < 2; ++m)
#pragma unroll
        for (int n = 0; n < 8; ++n) acc[m][n] = (f32x4){0.f, 0.f, 0.f, 0.f};

    int lr = lane & 15, lk = (lane >> 4) * 8;
    const unsigned short* pA = &As[(wr * 32 + lr) * 32 + lk];
    const unsigned short* pB = &Bs[(wc * 128 + lr) * 32 + lk];

    for (int kt = 0; kt < K; kt += 32) {
        __builtin_amdgcn_global_load_lds((const __attribute__((address_space(1))) void*)gA,
                                         (__attribute__((address_space(3))) void*)lA0, 16, 0, 0);
#pragma unroll
        for (int c = 0; c < 4; ++c)
            __builtin_amdgcn_global_load_lds(
                (const __attribute__((address_space(1))) void*)(gB + (size_t)(c * 16) * K),
                (__attribute__((address_space(3))) void*)(lB0 + c * 1024), 16, 0, 0);
        gA += 32; gB += 32;
        __syncthreads();
        bf16x8 a[2], b[8];
#pragma unroll
        for (int m = 0; m < 2; ++m) a[m] = *(const bf16x8*)(pA + m * 16 * 32);
#pragma unroll
        for (int n = 0; n < 8; ++n) b[n] = *(const bf16x8*)(pB + n * 16 * 32);
#pragma unroll
        for (int m = 0; m < 2; ++m)
#pragma unroll
            for (int n = 0; n < 8; ++n)
                acc[m][n] = __builtin_amdgcn_mfma_f32_16x16x32_bf16(a[m], b[n], acc[m][n], 0, 0, 0);
        __syncthreads();
    }

    int fr = (lane >> 4) * 4, fc = lane & 15;
    float biasv[8], gv[8], bv[8];
#pragma unroll
    for (int n = 0; n < 8; ++n) {
        int c = wc * 128 + n * 16 + fc;
        biasv[n] = bias[c]; gv[n] = g[c]; bv[n] = bb[c];
    }
    // pass 1: add bias + residual, accumulate row stats over this wave's 128 cols
    float s1[2][4], s2[2][4];
#pragma unroll
    for (int m = 0; m < 2; ++m)
#pragma unroll
        for (int i = 0; i < 4; ++i) { s1[m][i] = 0.f; s2[m][i] = 0.f; }
#pragma unroll
    for (int m = 0; m < 2; ++m) {
#pragma unroll
        for (int i = 0; i < 4; ++i) {
            int row = row0 + wr * 32 + m * 16 + fr + i;
            const float* xr = &X[(size_t)row * 256 + wc * 128 + fc];
#pragma unroll
            for (int n = 0; n < 8; ++n) {
                float v = acc[m][n][i] + biasv[n] + xr[n * 16];
                acc[m][n][i] = v;
                s1[m][i] += v;
                s2[m][i] = fmaf(v, v, s2[m][i]);
            }
        }
    }
#pragma unroll
    for (int o = 1; o < 16; o <<= 1) {
#pragma unroll
        for (int m = 0; m < 2; ++m)
#pragma unroll
            for (int i = 0; i < 4; ++i) {
                s1[m][i] += __shfl_xor(s1[m][i], o, 16);
                s2[m][i] += __shfl_xor(s2[m][i], o, 16);
            }
    }
    if (fc == 0) {
#pragma unroll
        for (int m = 0; m < 2; ++m)
#pragma unroll
            for (int i = 0; i < 4; ++i) {
                int r = wr * 32 + m * 16 + fr + i;
                red[wc][0][r] = s1[m][i];
                red[wc][1][r] = s2[m][i];
            }
    }
    __syncthreads();
    // pass 2: LN transform + stores (lane writes exactly what it read -> in-place safe)
#pragma unroll
    for (int m = 0; m < 2; ++m) {
#pragma unroll
        for (int i = 0; i < 4; ++i) {
            int r = wr * 32 + m * 16 + fr + i;
            int row = row0 + r;
            if (row >= NQ_) continue;
            float t1 = red[0][0][r] + red[1][0][r];
            float t2 = red[0][1][r] + red[1][1][r];
            float mu = t1 * (1.f / 256.f);
            float inv = rsqrtf(t2 * (1.f / 256.f) - mu * mu + 1e-5f);
            float* orow = &O[(size_t)row * 256 + wc * 128 + fc];
#pragma unroll
            for (int n = 0; n < 8; ++n) {
                float y = (acc[m][n][i] - mu) * inv * gv[n] + bv[n];
                orow[n * 16] = y;
                if (Obf) Obf[(size_t)row * 256 + wc * 128 + n * 16 + fc] = f2bf(y);
                if (qbf) {
                    float pv = pos[(size_t)row * 256 + wc * 128 + n * 16 + fc];
                    qbf[(size_t)row * 256 + wc * 128 + n * 16 + fc] = f2bf(y + pv);
                }
            }
        }
    }
}

// ============ fused softmax + trilinear sampling (v5: 2 rows/block) ==========
// oa: [row][512] fp32 (0..383 offsets, 384..511 logits); value bf16.
// grid = NQ/2; block handles rows {r0, r0+1} of one XCD chunk.
__global__ __launch_bounds__(256) void k_sample(const float* __restrict__ oa,
                                                const unsigned short* __restrict__ vbf,
                                                unsigned short* __restrict__ aggbf) {
    int bid = blockIdx.x;
    int r0 = (bid & 7) * (NQ_ / 8) + (bid >> 3) * 2;   // XCD-chunked pair
    __shared__ float sw[2][8][128];
    __shared__ int sidx[2][8][128];
    int tid = threadIdx.x;
    const int dD[4] = {16, 8, 4, 2}, dH[4] = {32, 16, 8, 4}, dW[4] = {32, 16, 8, 4};
    const int loff[4] = {0, 16384, 18432, 18688};

    // phase 1: all 256 threads; rr = tid>>7 selects row of the pair
    {
        int rr = tid >> 7, t = tid & 127;
        int row = r0 + rr;
        int b = row / LEN_, qi = row - b * LEN_;
        int lq, s;
        if (qi < 16384)      { lq = 0; s = qi; }
        else if (qi < 18432) { lq = 1; s = qi - 16384; }
        else if (qi < 18688) { lq = 2; s = qi - 18432; }
        else                 { lq = 3; s = qi - 18688; }
        int Dq = dD[lq], Hq = dH[lq], Wq = dW[lq];
        int zq = s / (Hq * Wq);
        int rm = s - zq * (Hq * Wq);
        int yq = rm / Wq, xq = rm - (rm / Wq) * Wq;
        float ref0 = (zq + 0.5f) / Dq, ref1 = (yq + 0.5f) / Hq, ref2 = (xq + 0.5f) / Wq;

        int m = t >> 4, l = (t >> 2) & 3;
        float e = oa[(size_t)row * 512 + 384 + t];
        float mx = e;
#pragma unroll
        for (int o = 1; o < 16; o <<= 1) mx = fmaxf(mx, __shfl_xor(mx, o, 16));
        float ex = expf(e - mx);
        float sm = ex;
#pragma unroll
        for (int o = 1; o < 16; o <<= 1) sm += __shfl_xor(sm, o, 16);
        float aw = ex / sm;

        const int D_ = dD[l], H_ = dH[l], W_ = dW[l];
        float o0 = oa[(size_t)row * 512 + t * 3 + 0];
        float o1 = oa[(size_t)row * 512 + t * 3 + 1];
        float o2 = oa[(size_t)row * 512 + t * 3 + 2];
        float x = (ref0 + o0 / W_) * W_ - 0.5f;
        float y = (ref1 + o1 / H_) * H_ - 0.5f;
        float z = (ref2 + o2 / D_) * D_ - 0.5f;
        float xf = floorf(x), yf = floorf(y), zf = floorf(z);
        float fx = x - xf, fy = y - yf, fz = z - zf;
        int x0 = (int)xf, y0 = (int)yf, z0 = (int)zf;
        int vbase = (b * LEN_ + loff[l]) * DM_ + m * 32;
#pragma unroll
        for (int dz = 0; dz < 2; ++dz)
#pragma unroll
            for (int dy = 0; dy < 2; ++dy)
#pragma unroll
                for (int dx = 0; dx < 2; ++dx) {
                    int xi = x0 + dx, yi = y0 + dy, zi = z0 + dz;
                    float wgt = (dx ? fx : 1.f - fx) * (dy ? fy : 1.f - fy) * (dz ? fz : 1.f - fz);
                    bool valid = (xi >= 0) & (xi < W_) & (yi >= 0) & (yi < H_) &
                                 (zi >= 0) & (zi < D_);
                    int xc = min(max(xi, 0), W_ - 1);
                    int yc = min(max(yi, 0), H_ - 1);
                    int zc = min(max(zi, 0), D_ - 1);
                    int idx = (zc * H_ + yc) * W_ + xc;
                    int cr = (dz << 2) | (dy << 1) | dx;
                    sw[rr][cr][t] = valid ? aw * wgt : 0.f;
                    sidx[rr][cr][t] = vbase + idx * DM_;
                }
    }
    __syncthreads();

    // phase 2: both rows, all 256 threads each
    int m = tid >> 5;
    int lane5 = tid & 31;
    int sub = lane5 >> 2, cg = lane5 & 3;
#pragma unroll
    for (int rr = 0; rr < 2; ++rr) {
        int row = r0 + rr;
        float acc[8];
#pragma unroll
        for (int i = 0; i < 8; ++i) acc[i] = 0.f;
#pragma unroll
        for (int t = 0; t < 16; ++t) {
            int pair = sub * 16 + t;           // 128 (point,corner) pairs
            int tq = pair >> 3, cr = pair & 7;
            float wq = sw[rr][cr][m * 16 + tq];
            int ofs = sidx[rr][cr][m * 16 + tq];
            uint4 v = *(const uint4*)&vbf[ofs + cg * 8];
            acc[0] = fmaf(wq, __uint_as_float(v.x << 16), acc[0]);
            acc[1] = fmaf(wq, __uint_as_float(v.x & 0xffff0000u), acc[1]);
            acc[2] = fmaf(wq, __uint_as_float(v.y << 16), acc[2]);
            acc[3] = fmaf(wq, __uint_as_float(v.y & 0xffff0000u), acc[3]);
            acc[4] = fmaf(wq, __uint_as_float(v.z << 16), acc[4]);
            acc[5] = fmaf(wq, __uint_as_float(v.z & 0xffff0000u), acc[5]);
            acc[6] = fmaf(wq, __uint_as_float(v.w << 16), acc[6]);
            acc[7] = fmaf(wq, __uint_as_float(v.w & 0xffff0000u), acc[7]);
        }
#pragma unroll
        for (int i = 0; i < 8; ++i) {
            acc[i] += __shfl_xor(acc[i], 4, 64);
            acc[i] += __shfl_xor(acc[i], 8, 64);
            acc[i] += __shfl_xor(acc[i], 16, 64);
        }
        if (sub == 0) {
            uint4 o;
            o.x = ((unsigned)f2bf(acc[1]) << 16) | f2bf(acc[0]);
            o.y = ((unsigned)f2bf(acc[3]) << 16) | f2bf(acc[2]);
            o.z = ((unsigned)f2bf(acc[5]) << 16) | f2bf(acc[4]);
            o.w = ((unsigned)f2bf(acc[7]) << 16) | f2bf(acc[6]);
            *(uint4*)&aggbf[(size_t)row * DM_ + m * 32 + cg * 8] = o;
        }
    }
}

extern "C" void kernel_launch(void* const* d_in, const int* in_sizes, int n_in,
                              void* d_out, int out_size, void* d_ws, size_t ws_size,
                              hipStream_t stream) {
    const float* lemb  = (const float*)d_in[8];
    const float* W_off = (const float*)d_in[9];
    const float* bOff  = (const float*)d_in[10];
    const float* W_att = (const float*)d_in[11];
    const float* bAtt  = (const float*)d_in[12];
    const float* W_val = (const float*)d_in[13];
    const float* bVal  = (const float*)d_in[14];
    const float* W_out = (const float*)d_in[15];
    const float* bOut  = (const float*)d_in[16];
    const float* ln1g  = (const float*)d_in[17];
    const float* ln1b  = (const float*)d_in[18];
    const float* W_ff1 = (const float*)d_in[19];
    const float* bFf1  = (const float*)d_in[20];
    const float* W_ff2 = (const float*)d_in[21];
    const float* bFf2  = (const float*)d_in[22];
    const float* ln2g  = (const float*)d_in[23];
    const float* ln2b  = (const float*)d_in[24];

    // ---- workspace layout (byte offsets) ----
    char* ws = (char*)d_ws;
    const size_t NR = (size_t)NQP_ * 256;
    float* b_src = (float*)ws;                                   // NR f32
    float* b_pos = (float*)(ws + NR * 4);                        // NR f32
    unsigned short* b_srcbf = (unsigned short*)(ws + NR * 8);    // NR bf16
    unsigned short* b_qbf   = (unsigned short*)(ws + NR * 10);   // NR bf16
    unsigned short* b_wt    = (unsigned short*)(ws + NR * 12);   // 2*786432 bf16
    char* R = ws + NR * 12 + (size_t)2 * 786432 * 2;
    unsigned short* b_valbf = (unsigned short*)(R);              // NR bf16   [R..R+2NR)
    float* b_oa             = (float*)(R + NR * 2);              // NQP*512 f32 [R+2NR..R+10NR)
    unsigned short* b_aggbf = (unsigned short*)(R + NR * 10);    // NR bf16  [R+10NR..R+12NR)
    unsigned short* b_ffhbf = (unsigned short*)(R + NR * 4);     // NQP*1024 bf16 [R+4NR..R+12NR)

    // ---- weight prep: one kernel, 12 transposes ----
    WPArgs wa;
    int start = 0;
    for (int l = 0; l < NL_; ++l) {
        unsigned short* wt = b_wt + (size_t)l * 786432;
        WPEnt ents[6] = {
            {W_val + (size_t)l * 65536,  wt + 0,      256, 256,  start},
            {W_off + (size_t)l * 98304,  wt + 65536,  256, 384,  start + 64},
            {W_att + (size_t)l * 32768,  wt + 163840, 256, 128,  start + 160},
            {W_out + (size_t)l * 65536,  wt + 196608, 256, 256,  start + 192},
            {W_ff1 + (size_t)l * 262144, wt + 262144, 256, 1024, start + 256},
            {W_ff2 + (size_t)l * 262144, wt + 524288, 1024, 256, start + 512},
        };
        for (int j = 0; j < 6; ++j) wa.e[l * 6 + j] = ents[j];
        start += 768;
    }
    k_wprep_all<<<dim3(1536), 256, 0, stream>>>(wa);

    FlatArgs fa;
    for (int i = 0; i < 4; ++i) {
        fa.s[i] = (const float*)d_in[2 * i];
        fa.p[i] = (const float*)d_in[2 * i + 1];
    }
    k_flatten<<<dim3(NQ_), 256, 0, stream>>>(fa, lemb, b_src, b_srcbf, b_pos, b_qbf);

    const int GR = NQP_ / 128;   // 293
    const int GL = NQP_ / 64;    // 586 (gemm_ln grid)
    const int BIG = 1 << 30;
    for (int l = 0; l < NL_; ++l) {
        unsigned short* wt = b_wt + (size_t)l * 786432;
        int last = (l == NL_ - 1);
        k_gemm<256, 2><<<dim3(GR, 2), 256, 0, stream>>>(
            b_srcbf, wt + 0, bVal + l * 256, bVal + l * 256, BIG, nullptr, b_valbf, 256);
        k_gemm<256, 0><<<dim3(GR, 4), 256, 0, stream>>>(
            b_qbf, wt + 65536, bOff + l * 384, bAtt + l * 128, 384, b_oa, nullptr, 512);
        k_sample<<<dim3(NQ_ / 2), 256, 0, stream>>>(b_oa, b_valbf, b_aggbf);
        // out-proj + residual + LN1 (in-place on b_src, refresh b_srcbf)
        k_gemm_ln<256><<<dim3(GL), 256, 0, stream>>>(
            b_aggbf, wt + 196608, bOut + l * 256, b_src, ln1g + l * 256, ln1b + l * 256,
            b_src, b_srcbf, nullptr, nullptr);
        k_gemm<256, 1><<<dim3(GR, 8), 256, 0, stream>>>(
            b_srcbf, wt + 262144, bFf1 + l * 1024, bFf1 + l * 1024, BIG, nullptr, b_ffhbf, 1024);
        // ff2 + residual + LN2 (+ next-layer srcbf/qbf)
        float* dst = last ? (float*)d_out : b_src;
        k_gemm_ln<1024><<<dim3(GL), 256, 0, stream>>>(
            b_ffhbf, wt + 524288, bFf2 + l * 256, b_src, ln2g + l * 256, ln2b + l * 256,
            dst, last ? nullptr : b_srcbf,
            last ? nullptr : b_pos, last ? nullptr : b_qbf);
    }
}

// Round 16
// 746.784 us; speedup vs baseline: 1.0730x; 1.0730x over previous
//
#include <hip/hip_runtime.h>
#include <hip/hip_bf16.h>
#include <math.h>

typedef __attribute__((ext_vector_type(4))) float f32x4;
typedef __attribute__((ext_vector_type(8))) short bf16x8;

static constexpr int B_   = 2;
static constexpr int DM_  = 256;
static constexpr int NL_  = 2;
static constexpr int LEN_ = 18720;
static constexpr int NQ_  = 37440;           // B*LEN
static constexpr int NQP_ = 37504;           // 128*293

__device__ __forceinline__ unsigned short f2bf(float x) {
    __hip_bfloat16 h = __float2bfloat16(x);
    return *reinterpret_cast<unsigned short*>(&h);
}
__device__ __forceinline__ float bf2f(unsigned short u) {
    unsigned int v = ((unsigned int)u) << 16;
    return __uint_as_float(v);
}

// ============ flatten: all levels in one kernel; emits src f32/bf16, pos, qbf ===
struct FlatArgs { const float* s[4]; const float* p[4]; };
__global__ __launch_bounds__(256) void k_flatten(FlatArgs a, const float* __restrict__ lemb,
                                                 float* __restrict__ src,
                                                 unsigned short* __restrict__ srcbf,
                                                 float* __restrict__ pos,
                                                 unsigned short* __restrict__ qbf) {
    int t = blockIdx.x, c = threadIdx.x;
    int l, rel;
    if (t < 32768)      { l = 0; rel = t; }
    else if (t < 36864) { l = 1; rel = t - 32768; }
    else if (t < 37376) { l = 2; rel = t - 36864; }
    else                { l = 3; rel = t - 37376; }
    const int SH[4] = {14, 11, 8, 5};            // log2(S)
    const int OFF[4] = {0, 16384, 18432, 18688};
    int S = 1 << SH[l];
    int b = rel >> SH[l], s = rel & (S - 1);
    float sv = a.s[l][(size_t)(b * DM_ + c) * S + s];
    float pv = a.p[l][(size_t)(b * DM_ + c) * S + s] + lemb[l * DM_ + c];
    size_t row = (size_t)b * LEN_ + OFF[l] + s;
    src[row * DM_ + c] = sv;
    srcbf[row * DM_ + c] = f2bf(sv);
    pos[row * DM_ + c] = pv;
    qbf[row * DM_ + c] = f2bf(sv + pv);
}

// ============ weight prep: all transposes in one kernel ============
struct WPEnt { const float* s; unsigned short* d; int K, N, start; };
struct WPArgs { WPEnt e[12]; };
__global__ __launch_bounds__(256) void k_wprep_all(WPArgs a) {
    __shared__ float t[32][33];
    int bidx = blockIdx.x;
    int i = 0;
#pragma unroll
    for (int j = 1; j < 12; ++j) if (bidx >= a.e[j].start) i = j;
    const float* W = a.e[i].s;
    unsigned short* Wt = a.e[i].d;
    int K = a.e[i].K, N = a.e[i].N;
    int ti = bidx - a.e[i].start;
    int tilesX = N >> 5;
    int bx = ti % tilesX, by = ti / tilesX;
    int n0 = bx * 32, k0 = by * 32;
    int tx = threadIdx.x & 31, ty = threadIdx.x >> 5;
#pragma unroll
    for (int q = 0; q < 4; ++q)
        t[ty + q * 8][tx] = W[(size_t)(k0 + ty + q * 8) * N + n0 + tx];
    __syncthreads();
#pragma unroll
    for (int q = 0; q < 4; ++q)
        Wt[(size_t)(n0 + ty + q * 8) * K + k0 + tx] = f2bf(t[tx][ty + q * 8]);
}

// ============ bf16 MFMA GEMM, 128x128 tile, BK=32 ============
// MODE 0: C fp32.  MODE 1: relu -> Cbf bf16.  MODE 2: Cbf bf16.
template<int K, int MODE>
__global__ __launch_bounds__(256) void k_gemm(const unsigned short* __restrict__ A,
                                              const unsigned short* __restrict__ Bt,
                                              const float* __restrict__ bias,
                                              const float* __restrict__ bias2,
                                              int nsplit,
                                              float* __restrict__ C,
                                              unsigned short* __restrict__ Cbf,
                                              int N) {
    __shared__ unsigned short As[128 * 32];
    __shared__ unsigned short Bs[128 * 32];
    int tid = threadIdx.x;
    int w = tid >> 6, lane = tid & 63;
    int wr = w >> 1, wc = w & 1;
    int row0 = blockIdx.x * 128, col0 = blockIdx.y * 128;

    const unsigned short* gA = A + (size_t)(row0 + w * 32 + (lane >> 2)) * K + (lane & 3) * 8;
    const unsigned short* gB = Bt + (size_t)(col0 + w * 32 + (lane >> 2)) * K + (lane & 3) * 8;
    char* lA0 = (char*)As + w * 2048;
    char* lB0 = (char*)Bs + w * 2048;

    f32x4 acc[4][4];
#pragma unroll
    for (int m = 0; m < 4; ++m)
#pragma unroll
        for (int n = 0; n < 4; ++n) acc[m][n] = (f32x4){0.f, 0.f, 0.f, 0.f};

    int lr = lane & 15, lk = (lane >> 4) * 8;
    const unsigned short* pA = &As[(wr * 64 + lr) * 32 + lk];
    const unsigned short* pB = &Bs[(wc * 64 + lr) * 32 + lk];

    for (int kt = 0; kt < K; kt += 32) {
        __builtin_amdgcn_global_load_lds((const __attribute__((address_space(1))) void*)gA,
                                         (__attribute__((address_space(3))) void*)lA0, 16, 0, 0);
        __builtin_amdgcn_global_load_lds((const __attribute__((address_space(1))) void*)(gA + (size_t)16 * K),
                                         (__attribute__((address_space(3))) void*)(lA0 + 1024), 16, 0, 0);
        __builtin_amdgcn_global_load_lds((const __attribute__((address_space(1))) void*)gB,
                                         (__attribute__((address_space(3))) void*)lB0, 16, 0, 0);
        __builtin_amdgcn_global_load_lds((const __attribute__((address_space(1))) void*)(gB + (size_t)16 * K),
                                         (__attribute__((address_space(3))) void*)(lB0 + 1024), 16, 0, 0);
        gA += 32; gB += 32;
        __syncthreads();
        bf16x8 a[4], b[4];
#pragma unroll
        for (int m = 0; m < 4; ++m) a[m] = *(const bf16x8*)(pA + m * 16 * 32);
#pragma unroll
        for (int n = 0; n < 4; ++n) b[n] = *(const bf16x8*)(pB + n * 16 * 32);
#pragma unroll
        for (int m = 0; m < 4; ++m)
#pragma unroll
            for (int n = 0; n < 4; ++n)
                acc[m][n] = __builtin_amdgcn_mfma_f32_16x16x32_bf16(a[m], b[n], acc[m][n], 0, 0, 0);
        __syncthreads();
    }

    int fr = (lane >> 4) * 4, fc = lane & 15;
#pragma unroll
    for (int m = 0; m < 4; ++m) {
#pragma unroll
        for (int n = 0; n < 4; ++n) {
            int cc = col0 + wc * 64 + n * 16 + fc;
            float bv = (cc < nsplit) ? bias[cc] : bias2[cc - nsplit];
#pragma unroll
            for (int i = 0; i < 4; ++i) {
                int cr = row0 + wr * 64 + m * 16 + fr + i;
                float v = acc[m][n][i] + bv;
                if (MODE == 1) {
                    Cbf[(size_t)cr * N + cc] = f2bf(fmaxf(v, 0.f));
                } else if (MODE == 2) {
                    Cbf[(size_t)cr * N + cc] = f2bf(v);
                } else {
                    C[(size_t)cr * N + cc] = v;
                }
            }
        }
    }
}

// ============ fused softmax + trilinear sampling (v5: 2 rows/block) ==========
// oa: [row][512] fp32 (0..383 offsets, 384..511 logits); value bf16.
// grid = NQ/2; block handles rows {r0, r0+1} of one XCD chunk.
__global__ __launch_bounds__(256) void k_sample(const float* __restrict__ oa,
                                                const unsigned short* __restrict__ vbf,
                                                unsigned short* __restrict__ aggbf) {
    int bid = blockIdx.x;
    int r0 = (bid & 7) * (NQ_ / 8) + (bid >> 3) * 2;   // XCD-chunked pair
    __shared__ float sw[2][8][128];
    __shared__ int sidx[2][8][128];
    int tid = threadIdx.x;
    const int dD[4] = {16, 8, 4, 2}, dH[4] = {32, 16, 8, 4}, dW[4] = {32, 16, 8, 4};
    const int loff[4] = {0, 16384, 18432, 18688};

    // phase 1: all 256 threads; rr = tid>>7 selects row of the pair
    {
        int rr = tid >> 7, t = tid & 127;
        int row = r0 + rr;
        int b = row / LEN_, qi = row - b * LEN_;
        int lq, s;
        if (qi < 16384)      { lq = 0; s = qi; }
        else if (qi < 18432) { lq = 1; s = qi - 16384; }
        else if (qi < 18688) { lq = 2; s = qi - 18432; }
        else                 { lq = 3; s = qi - 18688; }
        int Dq = dD[lq], Hq = dH[lq], Wq = dW[lq];
        int zq = s / (Hq * Wq);
        int rm = s - zq * (Hq * Wq);
        int yq = rm / Wq, xq = rm - (rm / Wq) * Wq;
        float ref0 = (zq + 0.5f) / Dq, ref1 = (yq + 0.5f) / Hq, ref2 = (xq + 0.5f) / Wq;

        int m = t >> 4, l = (t >> 2) & 3;
        float e = oa[(size_t)row * 512 + 384 + t];
        float mx = e;
#pragma unroll
        for (int o = 1; o < 16; o <<= 1) mx = fmaxf(mx, __shfl_xor(mx, o, 16));
        float ex = expf(e - mx);
        float sm = ex;
#pragma unroll
        for (int o = 1; o < 16; o <<= 1) sm += __shfl_xor(sm, o, 16);
        float aw = ex / sm;

        const int D_ = dD[l], H_ = dH[l], W_ = dW[l];
        float o0 = oa[(size_t)row * 512 + t * 3 + 0];
        float o1 = oa[(size_t)row * 512 + t * 3 + 1];
        float o2 = oa[(size_t)row * 512 + t * 3 + 2];
        float x = (ref0 + o0 / W_) * W_ - 0.5f;
        float y = (ref1 + o1 / H_) * H_ - 0.5f;
        float z = (ref2 + o2 / D_) * D_ - 0.5f;
        float xf = floorf(x), yf = floorf(y), zf = floorf(z);
        float fx = x - xf, fy = y - yf, fz = z - zf;
        int x0 = (int)xf, y0 = (int)yf, z0 = (int)zf;
        int vbase = (b * LEN_ + loff[l]) * DM_ + m * 32;
#pragma unroll
        for (int dz = 0; dz < 2; ++dz)
#pragma unroll
            for (int dy = 0; dy < 2; ++dy)
#pragma unroll
                for (int dx = 0; dx < 2; ++dx) {
                    int xi = x0 + dx, yi = y0 + dy, zi = z0 + dz;
                    float wgt = (dx ? fx : 1.f - fx) * (dy ? fy : 1.f - fy) * (dz ? fz : 1.f - fz);
                    bool valid = (xi >= 0) & (xi < W_) & (yi >= 0) & (yi < H_) &
                                 (zi >= 0) & (zi < D_);
                    int xc = min(max(xi, 0), W_ - 1);
                    int yc = min(max(yi, 0), H_ - 1);
                    int zc = min(max(zi, 0), D_ - 1);
                    int idx = (zc * H_ + yc) * W_ + xc;
                    int cr = (dz << 2) | (dy << 1) | dx;
                    sw[rr][cr][t] = valid ? aw * wgt : 0.f;
                    sidx[rr][cr][t] = vbase + idx * DM_;
                }
    }
    __syncthreads();

    // phase 2: both rows, all 256 threads each
    int m = tid >> 5;
    int lane5 = tid & 31;
    int sub = lane5 >> 2, cg = lane5 & 3;
#pragma unroll
    for (int rr = 0; rr < 2; ++rr) {
        int row = r0 + rr;
        float acc[8];
#pragma unroll
        for (int i = 0; i < 8; ++i) acc[i] = 0.f;
#pragma unroll
        for (int t = 0; t < 16; ++t) {
            int pair = sub * 16 + t;           // 128 (point,corner) pairs
            int tq = pair >> 3, cr = pair & 7;
            float wq = sw[rr][cr][m * 16 + tq];
            int ofs = sidx[rr][cr][m * 16 + tq];
            uint4 v = *(const uint4*)&vbf[ofs + cg * 8];
            acc[0] = fmaf(wq, __uint_as_float(v.x << 16), acc[0]);
            acc[1] = fmaf(wq, __uint_as_float(v.x & 0xffff0000u), acc[1]);
            acc[2] = fmaf(wq, __uint_as_float(v.y << 16), acc[2]);
            acc[3] = fmaf(wq, __uint_as_float(v.y & 0xffff0000u), acc[3]);
            acc[4] = fmaf(wq, __uint_as_float(v.z << 16), acc[4]);
            acc[5] = fmaf(wq, __uint_as_float(v.z & 0xffff0000u), acc[5]);
            acc[6] = fmaf(wq, __uint_as_float(v.w << 16), acc[6]);
            acc[7] = fmaf(wq, __uint_as_float(v.w & 0xffff0000u), acc[7]);
        }
#pragma unroll
        for (int i = 0; i < 8; ++i) {
            acc[i] += __shfl_xor(acc[i], 4, 64);
            acc[i] += __shfl_xor(acc[i], 8, 64);
            acc[i] += __shfl_xor(acc[i], 16, 64);
        }
        if (sub == 0) {
            uint4 o;
            o.x = ((unsigned)f2bf(acc[1]) << 16) | f2bf(acc[0]);
            o.y = ((unsigned)f2bf(acc[3]) << 16) | f2bf(acc[2]);
            o.z = ((unsigned)f2bf(acc[5]) << 16) | f2bf(acc[4]);
            o.w = ((unsigned)f2bf(acc[7]) << 16) | f2bf(acc[6]);
            *(uint4*)&aggbf[(size_t)row * DM_ + m * 32 + cg * 8] = o;
        }
    }
}

// ============ fused residual-add + LayerNorm; residual R in bf16 =============
__global__ __launch_bounds__(256) void k_add_ln(const float* __restrict__ X,
                                                const unsigned short* __restrict__ Rr,
                                                const float* __restrict__ g,
                                                const float* __restrict__ bb,
                                                float* __restrict__ O,
                                                unsigned short* __restrict__ Obf,
                                                const float* __restrict__ pos,
                                                unsigned short* __restrict__ qbf) {
    int wid = threadIdx.x >> 6, lane = threadIdx.x & 63;
    size_t row = (size_t)blockIdx.x * 4 + wid;
    float4 x = ((const float4*)&X[row * DM_])[lane];
    ushort4 r4 = ((const ushort4*)&Rr[row * DM_])[lane];
    float v[4] = {x.x + bf2f(r4.x), x.y + bf2f(r4.y), x.z + bf2f(r4.z), x.w + bf2f(r4.w)};
    float sm = v[0] + v[1] + v[2] + v[3];
#pragma unroll
    for (int o = 32; o; o >>= 1) sm += __shfl_xor(sm, o, 64);
    float mu = sm * (1.f / 256.f);
    float q = 0.f;
#pragma unroll
    for (int i = 0; i < 4; ++i) { float d = v[i] - mu; q += d * d; }
#pragma unroll
    for (int o = 32; o; o >>= 1) q += __shfl_xor(q, o, 64);
    float inv = rsqrtf(q * (1.f / 256.f) + 1e-5f);
    int c0 = lane * 4;
    float4 gv = *(const float4*)&g[c0];
    float4 bv = *(const float4*)&bb[c0];
    float4 o4;
    o4.x = (v[0] - mu) * inv * gv.x + bv.x;
    o4.y = (v[1] - mu) * inv * gv.y + bv.y;
    o4.z = (v[2] - mu) * inv * gv.z + bv.z;
    o4.w = (v[3] - mu) * inv * gv.w + bv.w;
    ((float4*)&O[row * DM_])[lane] = o4;
    if (Obf) {
        ushort4 ob;
        ob.x = f2bf(o4.x); ob.y = f2bf(o4.y); ob.z = f2bf(o4.z); ob.w = f2bf(o4.w);
        ((ushort4*)&Obf[row * DM_])[lane] = ob;
    }
    if (qbf) {
        float4 pv = ((const float4*)&pos[row * DM_])[lane];
        ushort4 qb;
        qb.x = f2bf(o4.x + pv.x); qb.y = f2bf(o4.y + pv.y);
        qb.z = f2bf(o4.z + pv.z); qb.w = f2bf(o4.w + pv.w);
        ((ushort4*)&qbf[row * DM_])[lane] = qb;
    }
}

extern "C" void kernel_launch(void* const* d_in, const int* in_sizes, int n_in,
                              void* d_out, int out_size, void* d_ws, size_t ws_size,
                              hipStream_t stream) {
    const float* lemb  = (const float*)d_in[8];
    const float* W_off = (const float*)d_in[9];
    const float* bOff  = (const float*)d_in[10];
    const float* W_att = (const float*)d_in[11];
    const float* bAtt  = (const float*)d_in[12];
    const float* W_val = (const float*)d_in[13];
    const float* bVal  = (const float*)d_in[14];
    const float* W_out = (const float*)d_in[15];
    const float* bOut  = (const float*)d_in[16];
    const float* ln1g  = (const float*)d_in[17];
    const float* ln1b  = (const float*)d_in[18];
    const float* W_ff1 = (const float*)d_in[19];
    const float* bFf1  = (const float*)d_in[20];
    const float* W_ff2 = (const float*)d_in[21];
    const float* bFf2  = (const float*)d_in[22];
    const float* ln2g  = (const float*)d_in[23];
    const float* ln2b  = (const float*)d_in[24];

    // ---- workspace layout (byte offsets) ----
    char* ws = (char*)d_ws;
    const size_t NR = (size_t)NQP_ * 256;
    float* b_src = (float*)ws;                                   // NR f32
    float* b_pos = (float*)(ws + NR * 4);                        // NR f32
    unsigned short* b_srcbf = (unsigned short*)(ws + NR * 8);    // NR bf16
    unsigned short* b_qbf   = (unsigned short*)(ws + NR * 10);   // NR bf16
    unsigned short* b_wt    = (unsigned short*)(ws + NR * 12);   // 2*786432 bf16
    char* R = ws + NR * 12 + (size_t)2 * 786432 * 2;
    unsigned short* b_valbf = (unsigned short*)(R);              // NR bf16   [R..R+2NR)
    float* b_oa             = (float*)(R + NR * 2);              // NQP*512 f32 [R+2NR..R+10NR)
    unsigned short* b_aggbf = (unsigned short*)(R + NR * 10);    // NR bf16  [R+10NR..R+12NR)
    unsigned short* b_tmpbf = (unsigned short*)(R);              // NR bf16 [R..R+2NR) (valbf/oa dead by then)
    unsigned short* b_ffhbf = (unsigned short*)(R + NR * 4);     // NQP*1024 bf16 [R+4NR..R+12NR)
    unsigned short* b_tmp2bf = (unsigned short*)(R);             // NR bf16 [R..R+2NR) — disjoint from ffhbf

    // ---- weight prep: one kernel, 12 transposes ----
    WPArgs wa;
    int start = 0;
    for (int l = 0; l < NL_; ++l) {
        unsigned short* wt = b_wt + (size_t)l * 786432;
        WPEnt ents[6] = {
            {W_val + (size_t)l * 65536,  wt + 0,      256, 256,  start},
            {W_off + (size_t)l * 98304,  wt + 65536,  256, 384,  start + 64},
            {W_att + (size_t)l * 32768,  wt + 163840, 256, 128,  start + 160},
            {W_out + (size_t)l * 65536,  wt + 196608, 256, 256,  start + 192},
            {W_ff1 + (size_t)l * 262144, wt + 262144, 256, 1024, start + 256},
            {W_ff2 + (size_t)l * 262144, wt + 524288, 1024, 256, start + 512},
        };
        for (int j = 0; j < 6; ++j) wa.e[l * 6 + j] = ents[j];
        start += 768;
    }
    k_wprep_all<<<dim3(1536), 256, 0, stream>>>(wa);

    FlatArgs fa;
    for (int i = 0; i < 4; ++i) {
        fa.s[i] = (const float*)d_in[2 * i];
        fa.p[i] = (const float*)d_in[2 * i + 1];
    }
    k_flatten<<<dim3(NQ_), 256, 0, stream>>>(fa, lemb, b_src, b_srcbf, b_pos, b_qbf);

    const int GR = NQP_ / 128;  // 293
    const int BIG = 1 << 30;
    for (int l = 0; l < NL_; ++l) {
        unsigned short* wt = b_wt + (size_t)l * 786432;
        k_gemm<256, 2><<<dim3(GR, 2), 256, 0, stream>>>(
            b_srcbf, wt + 0, bVal + l * 256, bVal + l * 256, BIG, nullptr, b_valbf, 256);
        k_gemm<256, 0><<<dim3(GR, 4), 256, 0, stream>>>(
            b_qbf, wt + 65536, bOff + l * 384, bAtt + l * 128, 384, b_oa, nullptr, 512);
        k_sample<<<dim3(NQ_ / 2), 256, 0, stream>>>(b_oa, b_valbf, b_aggbf);
        k_gemm<256, 2><<<dim3(GR, 2), 256, 0, stream>>>(
            b_aggbf, wt + 196608, bOut + l * 256, bOut + l * 256, BIG, nullptr, b_tmpbf, 256);
        k_add_ln<<<dim3(NQ_ / 4), 256, 0, stream>>>(b_src, b_tmpbf, ln1g + l * 256,
                                                    ln1b + l * 256, b_src, b_srcbf,
                                                    nullptr, nullptr);
        k_gemm<256, 1><<<dim3(GR, 8), 256, 0, stream>>>(
            b_srcbf, wt + 262144, bFf1 + l * 1024, bFf1 + l * 1024, BIG, nullptr, b_ffhbf, 1024);
        k_gemm<1024, 2><<<dim3(GR, 2), 256, 0, stream>>>(
            b_ffhbf, wt + 524288, bFf2 + l * 256, bFf2 + l * 256, BIG, nullptr, b_tmp2bf, 256);
        float* dst = (l == NL_ - 1) ? (float*)d_out : b_src;
        int last = (l == NL_ - 1);
        k_add_ln<<<dim3(NQ_ / 4), 256, 0, stream>>>(b_src, b_tmp2bf, ln2g + l * 256,
                                                    ln2b + l * 256, dst,
                                                    last ? nullptr : b_srcbf,
                                                    last ? nullptr : b_pos,
                                                    last ? nullptr : b_qbf);
    }
}

// Round 17
// 740.696 us; speedup vs baseline: 1.0819x; 1.0082x over previous
//
#include <hip/hip_runtime.h>
#include <hip/hip_bf16.h>
#include <math.h>

typedef __attribute__((ext_vector_type(4))) float f32x4;
typedef __attribute__((ext_vector_type(8))) short bf16x8;

static constexpr int B_   = 2;
static constexpr int DM_  = 256;
static constexpr int NL_  = 2;
static constexpr int LEN_ = 18720;
static constexpr int NQ_  = 37440;           // B*LEN
static constexpr int NQP_ = 37504;           // 128*293

__device__ __forceinline__ unsigned short f2bf(float x) {
    __hip_bfloat16 h = __float2bfloat16(x);
    return *reinterpret_cast<unsigned short*>(&h);
}
__device__ __forceinline__ float bf2f(unsigned short u) {
    unsigned int v = ((unsigned int)u) << 16;
    return __uint_as_float(v);
}

// ============ flatten: all levels in one kernel; emits src f32/bf16, pos, qbf ===
struct FlatArgs { const float* s[4]; const float* p[4]; };
__global__ __launch_bounds__(256) void k_flatten(FlatArgs a, const float* __restrict__ lemb,
                                                 float* __restrict__ src,
                                                 unsigned short* __restrict__ srcbf,
                                                 float* __restrict__ pos,
                                                 unsigned short* __restrict__ qbf) {
    int t = blockIdx.x, c = threadIdx.x;
    int l, rel;
    if (t < 32768)      { l = 0; rel = t; }
    else if (t < 36864) { l = 1; rel = t - 32768; }
    else if (t < 37376) { l = 2; rel = t - 36864; }
    else                { l = 3; rel = t - 37376; }
    const int SH[4] = {14, 11, 8, 5};            // log2(S)
    const int OFF[4] = {0, 16384, 18432, 18688};
    int S = 1 << SH[l];
    int b = rel >> SH[l], s = rel & (S - 1);
    float sv = a.s[l][(size_t)(b * DM_ + c) * S + s];
    float pv = a.p[l][(size_t)(b * DM_ + c) * S + s] + lemb[l * DM_ + c];
    size_t row = (size_t)b * LEN_ + OFF[l] + s;
    src[row * DM_ + c] = sv;
    srcbf[row * DM_ + c] = f2bf(sv);
    pos[row * DM_ + c] = pv;
    qbf[row * DM_ + c] = f2bf(sv + pv);
}

// ============ weight prep: all transposes in one kernel ============
struct WPEnt { const float* s; unsigned short* d; int K, N, start; };
struct WPArgs { WPEnt e[12]; };
__global__ __launch_bounds__(256) void k_wprep_all(WPArgs a) {
    __shared__ float t[32][33];
    int bidx = blockIdx.x;
    int i = 0;
#pragma unroll
    for (int j = 1; j < 12; ++j) if (bidx >= a.e[j].start) i = j;
    const float* W = a.e[i].s;
    unsigned short* Wt = a.e[i].d;
    int K = a.e[i].K, N = a.e[i].N;
    int ti = bidx - a.e[i].start;
    int tilesX = N >> 5;
    int bx = ti % tilesX, by = ti / tilesX;
    int n0 = bx * 32, k0 = by * 32;
    int tx = threadIdx.x & 31, ty = threadIdx.x >> 5;
#pragma unroll
    for (int q = 0; q < 4; ++q)
        t[ty + q * 8][tx] = W[(size_t)(k0 + ty + q * 8) * N + n0 + tx];
    __syncthreads();
#pragma unroll
    for (int q = 0; q < 4; ++q)
        Wt[(size_t)(n0 + ty + q * 8) * K + k0 + tx] = f2bf(t[tx][ty + q * 8]);
}

// ============ bf16 MFMA GEMM, 128x128 tile, BK=32 ============
// MODE 0: C fp32.  MODE 1: relu -> Cbf bf16.  MODE 2: Cbf bf16.
template<int K, int MODE>
__global__ __launch_bounds__(256) void k_gemm(const unsigned short* __restrict__ A,
                                              const unsigned short* __restrict__ Bt,
                                              const float* __restrict__ bias,
                                              const float* __restrict__ bias2,
                                              int nsplit,
                                              float* __restrict__ C,
                                              unsigned short* __restrict__ Cbf,
                                              int N) {
    __shared__ unsigned short As[128 * 32];
    __shared__ unsigned short Bs[128 * 32];
    int tid = threadIdx.x;
    int w = tid >> 6, lane = tid & 63;
    int wr = w >> 1, wc = w & 1;
    int row0 = blockIdx.x * 128, col0 = blockIdx.y * 128;

    const unsigned short* gA = A + (size_t)(row0 + w * 32 + (lane >> 2)) * K + (lane & 3) * 8;
    const unsigned short* gB = Bt + (size_t)(col0 + w * 32 + (lane >> 2)) * K + (lane & 3) * 8;
    char* lA0 = (char*)As + w * 2048;
    char* lB0 = (char*)Bs + w * 2048;

    f32x4 acc[4][4];
#pragma unroll
    for (int m = 0; m < 4; ++m)
#pragma unroll
        for (int n = 0; n < 4; ++n) acc[m][n] = (f32x4){0.f, 0.f, 0.f, 0.f};

    int lr = lane & 15, lk = (lane >> 4) * 8;
    const unsigned short* pA = &As[(wr * 64 + lr) * 32 + lk];
    const unsigned short* pB = &Bs[(wc * 64 + lr) * 32 + lk];

    for (int kt = 0; kt < K; kt += 32) {
        __builtin_amdgcn_global_load_lds((const __attribute__((address_space(1))) void*)gA,
                                         (__attribute__((address_space(3))) void*)lA0, 16, 0, 0);
        __builtin_amdgcn_global_load_lds((const __attribute__((address_space(1))) void*)(gA + (size_t)16 * K),
                                         (__attribute__((address_space(3))) void*)(lA0 + 1024), 16, 0, 0);
        __builtin_amdgcn_global_load_lds((const __attribute__((address_space(1))) void*)gB,
                                         (__attribute__((address_space(3))) void*)lB0, 16, 0, 0);
        __builtin_amdgcn_global_load_lds((const __attribute__((address_space(1))) void*)(gB + (size_t)16 * K),
                                         (__attribute__((address_space(3))) void*)(lB0 + 1024), 16, 0, 0);
        gA += 32; gB += 32;
        __syncthreads();
        bf16x8 a[4], b[4];
#pragma unroll
        for (int m = 0; m < 4; ++m) a[m] = *(const bf16x8*)(pA + m * 16 * 32);
#pragma unroll
        for (int n = 0; n < 4; ++n) b[n] = *(const bf16x8*)(pB + n * 16 * 32);
#pragma unroll
        for (int m = 0; m < 4; ++m)
#pragma unroll
            for (int n = 0; n < 4; ++n)
                acc[m][n] = __builtin_amdgcn_mfma_f32_16x16x32_bf16(a[m], b[n], acc[m][n], 0, 0, 0);
        __syncthreads();
    }

    int fr = (lane >> 4) * 4, fc = lane & 15;
#pragma unroll
    for (int m = 0; m < 4; ++m) {
#pragma unroll
        for (int n = 0; n < 4; ++n) {
            int cc = col0 + wc * 64 + n * 16 + fc;
            float bv = (cc < nsplit) ? bias[cc] : bias2[cc - nsplit];
#pragma unroll
            for (int i = 0; i < 4; ++i) {
                int cr = row0 + wr * 64 + m * 16 + fr + i;
                float v = acc[m][n][i] + bv;
                if (MODE == 1) {
                    Cbf[(size_t)cr * N + cc] = f2bf(fmaxf(v, 0.f));
                } else if (MODE == 2) {
                    Cbf[(size_t)cr * N + cc] = f2bf(v);
                } else {
                    C[(size_t)cr * N + cc] = v;
                }
            }
        }
    }
}

// ============ fused softmax + trilinear sampling (v6: bf16 oa, 2 rows/block) ==
// oa: [row][512] bf16 (0..383 offsets, 384..511 logits); value bf16.
// grid = NQ/2; block handles rows {r0, r0+1} of one XCD chunk.
__global__ __launch_bounds__(256) void k_sample(const unsigned short* __restrict__ oa,
                                                const unsigned short* __restrict__ vbf,
                                                unsigned short* __restrict__ aggbf) {
    int bid = blockIdx.x;
    int r0 = (bid & 7) * (NQ_ / 8) + (bid >> 3) * 2;   // XCD-chunked pair
    __shared__ float sw[2][8][128];
    __shared__ int sidx[2][8][128];
    int tid = threadIdx.x;
    const int dD[4] = {16, 8, 4, 2}, dH[4] = {32, 16, 8, 4}, dW[4] = {32, 16, 8, 4};
    const int loff[4] = {0, 16384, 18432, 18688};

    // phase 1: all 256 threads; rr = tid>>7 selects row of the pair
    {
        int rr = tid >> 7, t = tid & 127;
        int row = r0 + rr;
        int b = row / LEN_, qi = row - b * LEN_;
        int lq, s;
        if (qi < 16384)      { lq = 0; s = qi; }
        else if (qi < 18432) { lq = 1; s = qi - 16384; }
        else if (qi < 18688) { lq = 2; s = qi - 18432; }
        else                 { lq = 3; s = qi - 18688; }
        int Dq = dD[lq], Hq = dH[lq], Wq = dW[lq];
        int zq = s / (Hq * Wq);
        int rm = s - zq * (Hq * Wq);
        int yq = rm / Wq, xq = rm - (rm / Wq) * Wq;
        float ref0 = (zq + 0.5f) / Dq, ref1 = (yq + 0.5f) / Hq, ref2 = (xq + 0.5f) / Wq;

        int m = t >> 4, l = (t >> 2) & 3;
        float e = bf2f(oa[(size_t)row * 512 + 384 + t]);
        float mx = e;
#pragma unroll
        for (int o = 1; o < 16; o <<= 1) mx = fmaxf(mx, __shfl_xor(mx, o, 16));
        float ex = expf(e - mx);
        float sm = ex;
#pragma unroll
        for (int o = 1; o < 16; o <<= 1) sm += __shfl_xor(sm, o, 16);
        float aw = ex / sm;

        const int D_ = dD[l], H_ = dH[l], W_ = dW[l];
        float o0 = bf2f(oa[(size_t)row * 512 + t * 3 + 0]);
        float o1 = bf2f(oa[(size_t)row * 512 + t * 3 + 1]);
        float o2 = bf2f(oa[(size_t)row * 512 + t * 3 + 2]);
        float x = (ref0 + o0 / W_) * W_ - 0.5f;
        float y = (ref1 + o1 / H_) * H_ - 0.5f;
        float z = (ref2 + o2 / D_) * D_ - 0.5f;
        float xf = floorf(x), yf = floorf(y), zf = floorf(z);
        float fx = x - xf, fy = y - yf, fz = z - zf;
        int x0 = (int)xf, y0 = (int)yf, z0 = (int)zf;
        int vbase = (b * LEN_ + loff[l]) * DM_ + m * 32;
#pragma unroll
        for (int dz = 0; dz < 2; ++dz)
#pragma unroll
            for (int dy = 0; dy < 2; ++dy)
#pragma unroll
                for (int dx = 0; dx < 2; ++dx) {
                    int xi = x0 + dx, yi = y0 + dy, zi = z0 + dz;
                    float wgt = (dx ? fx : 1.f - fx) * (dy ? fy : 1.f - fy) * (dz ? fz : 1.f - fz);
                    bool valid = (xi >= 0) & (xi < W_) & (yi >= 0) & (yi < H_) &
                                 (zi >= 0) & (zi < D_);
                    int xc = min(max(xi, 0), W_ - 1);
                    int yc = min(max(yi, 0), H_ - 1);
                    int zc = min(max(zi, 0), D_ - 1);
                    int idx = (zc * H_ + yc) * W_ + xc;
                    int cr = (dz << 2) | (dy << 1) | dx;
                    sw[rr][cr][t] = valid ? aw * wgt : 0.f;
                    sidx[rr][cr][t] = vbase + idx * DM_;
                }
    }
    __syncthreads();

    // phase 2: both rows, all 256 threads each
    int m = tid >> 5;
    int lane5 = tid & 31;
    int sub = lane5 >> 2, cg = lane5 & 3;
#pragma unroll
    for (int rr = 0; rr < 2; ++rr) {
        int row = r0 + rr;
        float acc[8];
#pragma unroll
        for (int i = 0; i < 8; ++i) acc[i] = 0.f;
#pragma unroll
        for (int t = 0; t < 16; ++t) {
            int pair = sub * 16 + t;           // 128 (point,corner) pairs
            int tq = pair >> 3, cr = pair & 7;
            float wq = sw[rr][cr][m * 16 + tq];
            int ofs = sidx[rr][cr][m * 16 + tq];
            uint4 v = *(const uint4*)&vbf[ofs + cg * 8];
            acc[0] = fmaf(wq, __uint_as_float(v.x << 16), acc[0]);
            acc[1] = fmaf(wq, __uint_as_float(v.x & 0xffff0000u), acc[1]);
            acc[2] = fmaf(wq, __uint_as_float(v.y << 16), acc[2]);
            acc[3] = fmaf(wq, __uint_as_float(v.y & 0xffff0000u), acc[3]);
            acc[4] = fmaf(wq, __uint_as_float(v.z << 16), acc[4]);
            acc[5] = fmaf(wq, __uint_as_float(v.z & 0xffff0000u), acc[5]);
            acc[6] = fmaf(wq, __uint_as_float(v.w << 16), acc[6]);
            acc[7] = fmaf(wq, __uint_as_float(v.w & 0xffff0000u), acc[7]);
        }
#pragma unroll
        for (int i = 0; i < 8; ++i) {
            acc[i] += __shfl_xor(acc[i], 4, 64);
            acc[i] += __shfl_xor(acc[i], 8, 64);
            acc[i] += __shfl_xor(acc[i], 16, 64);
        }
        if (sub == 0) {
            uint4 o;
            o.x = ((unsigned)f2bf(acc[1]) << 16) | f2bf(acc[0]);
            o.y = ((unsigned)f2bf(acc[3]) << 16) | f2bf(acc[2]);
            o.z = ((unsigned)f2bf(acc[5]) << 16) | f2bf(acc[4]);
            o.w = ((unsigned)f2bf(acc[7]) << 16) | f2bf(acc[6]);
            *(uint4*)&aggbf[(size_t)row * DM_ + m * 32 + cg * 8] = o;
        }
    }
}

// ============ fused residual-add + LayerNorm; residual R in bf16 =============
__global__ __launch_bounds__(256) void k_add_ln(const float* __restrict__ X,
                                                const unsigned short* __restrict__ Rr,
                                                const float* __restrict__ g,
                                                const float* __restrict__ bb,
                                                float* __restrict__ O,
                                                unsigned short* __restrict__ Obf,
                                                const float* __restrict__ pos,
                                                unsigned short* __restrict__ qbf) {
    int wid = threadIdx.x >> 6, lane = threadIdx.x & 63;
    size_t row = (size_t)blockIdx.x * 4 + wid;
    float4 x = ((const float4*)&X[row * DM_])[lane];
    ushort4 r4 = ((const ushort4*)&Rr[row * DM_])[lane];
    float v[4] = {x.x + bf2f(r4.x), x.y + bf2f(r4.y), x.z + bf2f(r4.z), x.w + bf2f(r4.w)};
    float sm = v[0] + v[1] + v[2] + v[3];
#pragma unroll
    for (int o = 32; o; o >>= 1) sm += __shfl_xor(sm, o, 64);
    float mu = sm * (1.f / 256.f);
    float q = 0.f;
#pragma unroll
    for (int i = 0; i < 4; ++i) { float d = v[i] - mu; q += d * d; }
#pragma unroll
    for (int o = 32; o; o >>= 1) q += __shfl_xor(q, o, 64);
    float inv = rsqrtf(q * (1.f / 256.f) + 1e-5f);
    int c0 = lane * 4;
    float4 gv = *(const float4*)&g[c0];
    float4 bv = *(const float4*)&bb[c0];
    float4 o4;
    o4.x = (v[0] - mu) * inv * gv.x + bv.x;
    o4.y = (v[1] - mu) * inv * gv.y + bv.y;
    o4.z = (v[2] - mu) * inv * gv.z + bv.z;
    o4.w = (v[3] - mu) * inv * gv.w + bv.w;
    ((float4*)&O[row * DM_])[lane] = o4;
    if (Obf) {
        ushort4 ob;
        ob.x = f2bf(o4.x); ob.y = f2bf(o4.y); ob.z = f2bf(o4.z); ob.w = f2bf(o4.w);
        ((ushort4*)&Obf[row * DM_])[lane] = ob;
    }
    if (qbf) {
        float4 pv = ((const float4*)&pos[row * DM_])[lane];
        ushort4 qb;
        qb.x = f2bf(o4.x + pv.x); qb.y = f2bf(o4.y + pv.y);
        qb.z = f2bf(o4.z + pv.z); qb.w = f2bf(o4.w + pv.w);
        ((ushort4*)&qbf[row * DM_])[lane] = qb;
    }
}

extern "C" void kernel_launch(void* const* d_in, const int* in_sizes, int n_in,
                              void* d_out, int out_size, void* d_ws, size_t ws_size,
                              hipStream_t stream) {
    const float* lemb  = (const float*)d_in[8];
    const float* W_off = (const float*)d_in[9];
    const float* bOff  = (const float*)d_in[10];
    const float* W_att = (const float*)d_in[11];
    const float* bAtt  = (const float*)d_in[12];
    const float* W_val = (const float*)d_in[13];
    const float* bVal  = (const float*)d_in[14];
    const float* W_out = (const float*)d_in[15];
    const float* bOut  = (const float*)d_in[16];
    const float* ln1g  = (const float*)d_in[17];
    const float* ln1b  = (const float*)d_in[18];
    const float* W_ff1 = (const float*)d_in[19];
    const float* bFf1  = (const float*)d_in[20];
    const float* W_ff2 = (const float*)d_in[21];
    const float* bFf2  = (const float*)d_in[22];
    const float* ln2g  = (const float*)d_in[23];
    const float* ln2b  = (const float*)d_in[24];

    // ---- workspace layout (byte offsets) ----
    char* ws = (char*)d_ws;
    const size_t NR = (size_t)NQP_ * 256;
    float* b_src = (float*)ws;                                   // NR f32
    float* b_pos = (float*)(ws + NR * 4);                        // NR f32
    unsigned short* b_srcbf = (unsigned short*)(ws + NR * 8);    // NR bf16
    unsigned short* b_qbf   = (unsigned short*)(ws + NR * 10);   // NR bf16
    unsigned short* b_wt    = (unsigned short*)(ws + NR * 12);   // 2*786432 bf16
    char* R = ws + NR * 12 + (size_t)2 * 786432 * 2;
    unsigned short* b_valbf = (unsigned short*)(R);              // NR bf16   [R..R+2NR)
    unsigned short* b_oabf  = (unsigned short*)(R + NR * 2);     // NQP*512 bf16 [R+2NR..R+6NR)
    unsigned short* b_aggbf = (unsigned short*)(R + NR * 10);    // NR bf16  [R+10NR..R+12NR)
    unsigned short* b_tmpbf = (unsigned short*)(R);              // NR bf16 [R..R+2NR) (valbf dead by then)
    unsigned short* b_ffhbf = (unsigned short*)(R + NR * 4);     // NQP*1024 bf16 [R+4NR..R+12NR) (oabf/aggbf dead)
    unsigned short* b_tmp2bf = (unsigned short*)(R);             // NR bf16 [R..R+2NR) — disjoint from ffhbf

    // ---- weight prep: one kernel, 12 transposes ----
    WPArgs wa;
    int start = 0;
    for (int l = 0; l < NL_; ++l) {
        unsigned short* wt = b_wt + (size_t)l * 786432;
        WPEnt ents[6] = {
            {W_val + (size_t)l * 65536,  wt + 0,      256, 256,  start},
            {W_off + (size_t)l * 98304,  wt + 65536,  256, 384,  start + 64},
            {W_att + (size_t)l * 32768,  wt + 163840, 256, 128,  start + 160},
            {W_out + (size_t)l * 65536,  wt + 196608, 256, 256,  start + 192},
            {W_ff1 + (size_t)l * 262144, wt + 262144, 256, 1024, start + 256},
            {W_ff2 + (size_t)l * 262144, wt + 524288, 1024, 256, start + 512},
        };
        for (int j = 0; j < 6; ++j) wa.e[l * 6 + j] = ents[j];
        start += 768;
    }
    k_wprep_all<<<dim3(1536), 256, 0, stream>>>(wa);

    FlatArgs fa;
    for (int i = 0; i < 4; ++i) {
        fa.s[i] = (const float*)d_in[2 * i];
        fa.p[i] = (const float*)d_in[2 * i + 1];
    }
    k_flatten<<<dim3(NQ_), 256, 0, stream>>>(fa, lemb, b_src, b_srcbf, b_pos, b_qbf);

    const int GR = NQP_ / 128;  // 293
    const int BIG = 1 << 30;
    for (int l = 0; l < NL_; ++l) {
        unsigned short* wt = b_wt + (size_t)l * 786432;
        k_gemm<256, 2><<<dim3(GR, 2), 256, 0, stream>>>(
            b_srcbf, wt + 0, bVal + l * 256, bVal + l * 256, BIG, nullptr, b_valbf, 256);
        k_gemm<256, 2><<<dim3(GR, 4), 256, 0, stream>>>(
            b_qbf, wt + 65536, bOff + l * 384, bAtt + l * 128, 384, nullptr, b_oabf, 512);
        k_sample<<<dim3(NQ_ / 2), 256, 0, stream>>>(b_oabf, b_valbf, b_aggbf);
        k_gemm<256, 2><<<dim3(GR, 2), 256, 0, stream>>>(
            b_aggbf, wt + 196608, bOut + l * 256, bOut + l * 256, BIG, nullptr, b_tmpbf, 256);
        k_add_ln<<<dim3(NQ_ / 4), 256, 0, stream>>>(b_src, b_tmpbf, ln1g + l * 256,
                                                    ln1b + l * 256, b_src, b_srcbf,
                                                    nullptr, nullptr);
        k_gemm<256, 1><<<dim3(GR, 8), 256, 0, stream>>>(
            b_srcbf, wt + 262144, bFf1 + l * 1024, bFf1 + l * 1024, BIG, nullptr, b_ffhbf, 1024);
        k_gemm<1024, 2><<<dim3(GR, 2), 256, 0, stream>>>(
            b_ffhbf, wt + 524288, bFf2 + l * 256, bFf2 + l * 256, BIG, nullptr, b_tmp2bf, 256);
        float* dst = (l == NL_ - 1) ? (float*)d_out : b_src;
        int last = (l == NL_ - 1);
        k_add_ln<<<dim3(NQ_ / 4), 256, 0, stream>>>(b_src, b_tmp2bf, ln2g + l * 256,
                                                    ln2b + l * 256, dst,
                                                    last ? nullptr : b_srcbf,
                                                    last ? nullptr : b_pos,
                                                    last ? nullptr : b_qbf);
    }
}

// Round 18
// 700.751 us; speedup vs baseline: 1.1435x; 1.0570x over previous
//
#include <hip/hip_runtime.h>
#include <hip/hip_bf16.h>
#include <math.h>

typedef __attribute__((ext_vector_type(4))) float f32x4;
typedef __attribute__((ext_vector_type(8))) short bf16x8;

static constexpr int B_   = 2;
static constexpr int DM_  = 256;
static constexpr int NL_  = 2;
static constexpr int LEN_ = 18720;
static constexpr int NQ_  = 37440;           // B*LEN
static constexpr int NQP_ = 37504;           // 128*293

__device__ __forceinline__ unsigned short f2bf(float x) {
    __hip_bfloat16 h = __float2bfloat16(x);
    return *reinterpret_cast<unsigned short*>(&h);
}
__device__ __forceinline__ float bf2f(unsigned short u) {
    unsigned int v = ((unsigned int)u) << 16;
    return __uint_as_float(v);
}

// ============ flatten: all levels; emits srcbf, pos, qbf (bf16 residual stream) ===
struct FlatArgs { const float* s[4]; const float* p[4]; };
__global__ __launch_bounds__(256) void k_flatten(FlatArgs a, const float* __restrict__ lemb,
                                                 unsigned short* __restrict__ srcbf,
                                                 float* __restrict__ pos,
                                                 unsigned short* __restrict__ qbf) {
    int t = blockIdx.x, c = threadIdx.x;
    int l, rel;
    if (t < 32768)      { l = 0; rel = t; }
    else if (t < 36864) { l = 1; rel = t - 32768; }
    else if (t < 37376) { l = 2; rel = t - 36864; }
    else                { l = 3; rel = t - 37376; }
    const int SH[4] = {14, 11, 8, 5};            // log2(S)
    const int OFF[4] = {0, 16384, 18432, 18688};
    int S = 1 << SH[l];
    int b = rel >> SH[l], s = rel & (S - 1);
    float sv = a.s[l][(size_t)(b * DM_ + c) * S + s];
    float pv = a.p[l][(size_t)(b * DM_ + c) * S + s] + lemb[l * DM_ + c];
    size_t row = (size_t)b * LEN_ + OFF[l] + s;
    srcbf[row * DM_ + c] = f2bf(sv);
    pos[row * DM_ + c] = pv;
    qbf[row * DM_ + c] = f2bf(sv + pv);
}

// ============ weight prep: all transposes in one kernel ============
struct WPEnt { const float* s; unsigned short* d; int K, N, start; };
struct WPArgs { WPEnt e[12]; };
__global__ __launch_bounds__(256) void k_wprep_all(WPArgs a) {
    __shared__ float t[32][33];
    int bidx = blockIdx.x;
    int i = 0;
#pragma unroll
    for (int j = 1; j < 12; ++j) if (bidx >= a.e[j].start) i = j;
    const float* W = a.e[i].s;
    unsigned short* Wt = a.e[i].d;
    int K = a.e[i].K, N = a.e[i].N;
    int ti = bidx - a.e[i].start;
    int tilesX = N >> 5;
    int bx = ti % tilesX, by = ti / tilesX;
    int n0 = bx * 32, k0 = by * 32;
    int tx = threadIdx.x & 31, ty = threadIdx.x >> 5;
#pragma unroll
    for (int q = 0; q < 4; ++q)
        t[ty + q * 8][tx] = W[(size_t)(k0 + ty + q * 8) * N + n0 + tx];
    __syncthreads();
#pragma unroll
    for (int q = 0; q < 4; ++q)
        Wt[(size_t)(n0 + ty + q * 8) * K + k0 + tx] = f2bf(t[tx][ty + q * 8]);
}

// ============ bf16 MFMA GEMM, 128x128 tile, BK=32 ============
// MODE 0: C fp32.  MODE 1: relu -> Cbf bf16.  MODE 2: Cbf bf16.
template<int K, int MODE>
__global__ __launch_bounds__(256) void k_gemm(const unsigned short* __restrict__ A,
                                              const unsigned short* __restrict__ Bt,
                                              const float* __restrict__ bias,
                                              const float* __restrict__ bias2,
                                              int nsplit,
                                              float* __restrict__ C,
                                              unsigned short* __restrict__ Cbf,
                                              int N) {
    __shared__ unsigned short As[128 * 32];
    __shared__ unsigned short Bs[128 * 32];
    int tid = threadIdx.x;
    int w = tid >> 6, lane = tid & 63;
    int wr = w >> 1, wc = w & 1;
    int row0 = blockIdx.x * 128, col0 = blockIdx.y * 128;

    const unsigned short* gA = A + (size_t)(row0 + w * 32 + (lane >> 2)) * K + (lane & 3) * 8;
    const unsigned short* gB = Bt + (size_t)(col0 + w * 32 + (lane >> 2)) * K + (lane & 3) * 8;
    char* lA0 = (char*)As + w * 2048;
    char* lB0 = (char*)Bs + w * 2048;

    f32x4 acc[4][4];
#pragma unroll
    for (int m = 0; m < 4; ++m)
#pragma unroll
        for (int n = 0; n < 4; ++n) acc[m][n] = (f32x4){0.f, 0.f, 0.f, 0.f};

    int lr = lane & 15, lk = (lane >> 4) * 8;
    const unsigned short* pA = &As[(wr * 64 + lr) * 32 + lk];
    const unsigned short* pB = &Bs[(wc * 64 + lr) * 32 + lk];

    for (int kt = 0; kt < K; kt += 32) {
        __builtin_amdgcn_global_load_lds((const __attribute__((address_space(1))) void*)gA,
                                         (__attribute__((address_space(3))) void*)lA0, 16, 0, 0);
        __builtin_amdgcn_global_load_lds((const __attribute__((address_space(1))) void*)(gA + (size_t)16 * K),
                                         (__attribute__((address_space(3))) void*)(lA0 + 1024), 16, 0, 0);
        __builtin_amdgcn_global_load_lds((const __attribute__((address_space(1))) void*)gB,
                                         (__attribute__((address_space(3))) void*)lB0, 16, 0, 0);
        __builtin_amdgcn_global_load_lds((const __attribute__((address_space(1))) void*)(gB + (size_t)16 * K),
                                         (__attribute__((address_space(3))) void*)(lB0 + 1024), 16, 0, 0);
        gA += 32; gB += 32;
        __syncthreads();
        bf16x8 a[4], b[4];
#pragma unroll
        for (int m = 0; m < 4; ++m) a[m] = *(const bf16x8*)(pA + m * 16 * 32);
#pragma unroll
        for (int n = 0; n < 4; ++n) b[n] = *(const bf16x8*)(pB + n * 16 * 32);
#pragma unroll
        for (int m = 0; m < 4; ++m)
#pragma unroll
            for (int n = 0; n < 4; ++n)
                acc[m][n] = __builtin_amdgcn_mfma_f32_16x16x32_bf16(a[m], b[n], acc[m][n], 0, 0, 0);
        __syncthreads();
    }

    int fr = (lane >> 4) * 4, fc = lane & 15;
#pragma unroll
    for (int m = 0; m < 4; ++m) {
#pragma unroll
        for (int n = 0; n < 4; ++n) {
            int cc = col0 + wc * 64 + n * 16 + fc;
            float bv = (cc < nsplit) ? bias[cc] : bias2[cc - nsplit];
#pragma unroll
            for (int i = 0; i < 4; ++i) {
                int cr = row0 + wr * 64 + m * 16 + fr + i;
                float v = acc[m][n][i] + bv;
                if (MODE == 1) {
                    Cbf[(size_t)cr * N + cc] = f2bf(fmaxf(v, 0.f));
                } else if (MODE == 2) {
                    Cbf[(size_t)cr * N + cc] = f2bf(v);
                } else {
                    C[(size_t)cr * N + cc] = v;
                }
            }
        }
    }
}

// ============ fused softmax + trilinear sampling (v6: bf16 oa, 2 rows/block) ==
__global__ __launch_bounds__(256) void k_sample(const unsigned short* __restrict__ oa,
                                                const unsigned short* __restrict__ vbf,
                                                unsigned short* __restrict__ aggbf) {
    int bid = blockIdx.x;
    int r0 = (bid & 7) * (NQ_ / 8) + (bid >> 3) * 2;   // XCD-chunked pair
    __shared__ float sw[2][8][128];
    __shared__ int sidx[2][8][128];
    int tid = threadIdx.x;
    const int dD[4] = {16, 8, 4, 2}, dH[4] = {32, 16, 8, 4}, dW[4] = {32, 16, 8, 4};
    const int loff[4] = {0, 16384, 18432, 18688};

    // phase 1: all 256 threads; rr = tid>>7 selects row of the pair
    {
        int rr = tid >> 7, t = tid & 127;
        int row = r0 + rr;
        int b = row / LEN_, qi = row - b * LEN_;
        int lq, s;
        if (qi < 16384)      { lq = 0; s = qi; }
        else if (qi < 18432) { lq = 1; s = qi - 16384; }
        else if (qi < 18688) { lq = 2; s = qi - 18432; }
        else                 { lq = 3; s = qi - 18688; }
        int Dq = dD[lq], Hq = dH[lq], Wq = dW[lq];
        int zq = s / (Hq * Wq);
        int rm = s - zq * (Hq * Wq);
        int yq = rm / Wq, xq = rm - (rm / Wq) * Wq;
        float ref0 = (zq + 0.5f) / Dq, ref1 = (yq + 0.5f) / Hq, ref2 = (xq + 0.5f) / Wq;

        int m = t >> 4, l = (t >> 2) & 3;
        float e = bf2f(oa[(size_t)row * 512 + 384 + t]);
        float mx = e;
#pragma unroll
        for (int o = 1; o < 16; o <<= 1) mx = fmaxf(mx, __shfl_xor(mx, o, 16));
        float ex = expf(e - mx);
        float sm = ex;
#pragma unroll
        for (int o = 1; o < 16; o <<= 1) sm += __shfl_xor(sm, o, 16);
        float aw = ex / sm;

        const int D_ = dD[l], H_ = dH[l], W_ = dW[l];
        float o0 = bf2f(oa[(size_t)row * 512 + t * 3 + 0]);
        float o1 = bf2f(oa[(size_t)row * 512 + t * 3 + 1]);
        float o2 = bf2f(oa[(size_t)row * 512 + t * 3 + 2]);
        float x = (ref0 + o0 / W_) * W_ - 0.5f;
        float y = (ref1 + o1 / H_) * H_ - 0.5f;
        float z = (ref2 + o2 / D_) * D_ - 0.5f;
        float xf = floorf(x), yf = floorf(y), zf = floorf(z);
        float fx = x - xf, fy = y - yf, fz = z - zf;
        int x0 = (int)xf, y0 = (int)yf, z0 = (int)zf;
        int vbase = (b * LEN_ + loff[l]) * DM_ + m * 32;
#pragma unroll
        for (int dz = 0; dz < 2; ++dz)
#pragma unroll
            for (int dy = 0; dy < 2; ++dy)
#pragma unroll
                for (int dx = 0; dx < 2; ++dx) {
                    int xi = x0 + dx, yi = y0 + dy, zi = z0 + dz;
                    float wgt = (dx ? fx : 1.f - fx) * (dy ? fy : 1.f - fy) * (dz ? fz : 1.f - fz);
                    bool valid = (xi >= 0) & (xi < W_) & (yi >= 0) & (yi < H_) &
                                 (zi >= 0) & (zi < D_);
                    int xc = min(max(xi, 0), W_ - 1);
                    int yc = min(max(yi, 0), H_ - 1);
                    int zc = min(max(zi, 0), D_ - 1);
                    int idx = (zc * H_ + yc) * W_ + xc;
                    int cr = (dz << 2) | (dy << 1) | dx;
                    sw[rr][cr][t] = valid ? aw * wgt : 0.f;
                    sidx[rr][cr][t] = vbase + idx * DM_;
                }
    }
    __syncthreads();

    // phase 2: both rows, all 256 threads each
    int m = tid >> 5;
    int lane5 = tid & 31;
    int sub = lane5 >> 2, cg = lane5 & 3;
#pragma unroll
    for (int rr = 0; rr < 2; ++rr) {
        int row = r0 + rr;
        float acc[8];
#pragma unroll
        for (int i = 0; i < 8; ++i) acc[i] = 0.f;
#pragma unroll
        for (int t = 0; t < 16; ++t) {
            int pair = sub * 16 + t;           // 128 (point,corner) pairs
            int tq = pair >> 3, cr = pair & 7;
            float wq = sw[rr][cr][m * 16 + tq];
            int ofs = sidx[rr][cr][m * 16 + tq];
            uint4 v = *(const uint4*)&vbf[ofs + cg * 8];
            acc[0] = fmaf(wq, __uint_as_float(v.x << 16), acc[0]);
            acc[1] = fmaf(wq, __uint_as_float(v.x & 0xffff0000u), acc[1]);
            acc[2] = fmaf(wq, __uint_as_float(v.y << 16), acc[2]);
            acc[3] = fmaf(wq, __uint_as_float(v.y & 0xffff0000u), acc[3]);
            acc[4] = fmaf(wq, __uint_as_float(v.z << 16), acc[4]);
            acc[5] = fmaf(wq, __uint_as_float(v.z & 0xffff0000u), acc[5]);
            acc[6] = fmaf(wq, __uint_as_float(v.w << 16), acc[6]);
            acc[7] = fmaf(wq, __uint_as_float(v.w & 0xffff0000u), acc[7]);
        }
#pragma unroll
        for (int i = 0; i < 8; ++i) {
            acc[i] += __shfl_xor(acc[i], 4, 64);
            acc[i] += __shfl_xor(acc[i], 8, 64);
            acc[i] += __shfl_xor(acc[i], 16, 64);
        }
        if (sub == 0) {
            uint4 o;
            o.x = ((unsigned)f2bf(acc[1]) << 16) | f2bf(acc[0]);
            o.y = ((unsigned)f2bf(acc[3]) << 16) | f2bf(acc[2]);
            o.z = ((unsigned)f2bf(acc[5]) << 16) | f2bf(acc[4]);
            o.w = ((unsigned)f2bf(acc[7]) << 16) | f2bf(acc[6]);
            *(uint4*)&aggbf[(size_t)row * DM_ + m * 32 + cg * 8] = o;
        }
    }
}

// ============ fused residual-add + LayerNorm; all-bf16 residual stream =======
// X, R bf16; out: Obf bf16 (optional), Ofp fp32 (optional, final output),
// qbf = bf16(out + pos) (optional).
__global__ __launch_bounds__(256) void k_add_ln(const unsigned short* __restrict__ X,
                                                const unsigned short* __restrict__ Rr,
                                                const float* __restrict__ g,
                                                const float* __restrict__ bb,
                                                unsigned short* __restrict__ Obf,
                                                float* __restrict__ Ofp,
                                                const float* __restrict__ pos,
                                                unsigned short* __restrict__ qbf) {
    int wid = threadIdx.x >> 6, lane = threadIdx.x & 63;
    size_t row = (size_t)blockIdx.x * 4 + wid;
    ushort4 x4 = ((const ushort4*)&X[row * DM_])[lane];
    ushort4 r4 = ((const ushort4*)&Rr[row * DM_])[lane];
    float v[4] = {bf2f(x4.x) + bf2f(r4.x), bf2f(x4.y) + bf2f(r4.y),
                  bf2f(x4.z) + bf2f(r4.z), bf2f(x4.w) + bf2f(r4.w)};
    float sm = v[0] + v[1] + v[2] + v[3];
#pragma unroll
    for (int o = 32; o; o >>= 1) sm += __shfl_xor(sm, o, 64);
    float mu = sm * (1.f / 256.f);
    float q = 0.f;
#pragma unroll
    for (int i = 0; i < 4; ++i) { float d = v[i] - mu; q += d * d; }
#pragma unroll
    for (int o = 32; o; o >>= 1) q += __shfl_xor(q, o, 64);
    float inv = rsqrtf(q * (1.f / 256.f) + 1e-5f);
    int c0 = lane * 4;
    float4 gv = *(const float4*)&g[c0];
    float4 bv = *(const float4*)&bb[c0];
    float4 o4;
    o4.x = (v[0] - mu) * inv * gv.x + bv.x;
    o4.y = (v[1] - mu) * inv * gv.y + bv.y;
    o4.z = (v[2] - mu) * inv * gv.z + bv.z;
    o4.w = (v[3] - mu) * inv * gv.w + bv.w;
    if (Obf) {
        ushort4 ob;
        ob.x = f2bf(o4.x); ob.y = f2bf(o4.y); ob.z = f2bf(o4.z); ob.w = f2bf(o4.w);
        ((ushort4*)&Obf[row * DM_])[lane] = ob;
    }
    if (Ofp) ((float4*)&Ofp[row * DM_])[lane] = o4;
    if (qbf) {
        float4 pv = ((const float4*)&pos[row * DM_])[lane];
        ushort4 qb;
        qb.x = f2bf(o4.x + pv.x); qb.y = f2bf(o4.y + pv.y);
        qb.z = f2bf(o4.z + pv.z); qb.w = f2bf(o4.w + pv.w);
        ((ushort4*)&qbf[row * DM_])[lane] = qb;
    }
}

extern "C" void kernel_launch(void* const* d_in, const int* in_sizes, int n_in,
                              void* d_out, int out_size, void* d_ws, size_t ws_size,
                              hipStream_t stream) {
    const float* lemb  = (const float*)d_in[8];
    const float* W_off = (const float*)d_in[9];
    const float* bOff  = (const float*)d_in[10];
    const float* W_att = (const float*)d_in[11];
    const float* bAtt  = (const float*)d_in[12];
    const float* W_val = (const float*)d_in[13];
    const float* bVal  = (const float*)d_in[14];
    const float* W_out = (const float*)d_in[15];
    const float* bOut  = (const float*)d_in[16];
    const float* ln1g  = (const float*)d_in[17];
    const float* ln1b  = (const float*)d_in[18];
    const float* W_ff1 = (const float*)d_in[19];
    const float* bFf1  = (const float*)d_in[20];
    const float* W_ff2 = (const float*)d_in[21];
    const float* bFf2  = (const float*)d_in[22];
    const float* ln2g  = (const float*)d_in[23];
    const float* ln2b  = (const float*)d_in[24];

    // ---- workspace layout (byte offsets) ----
    char* ws = (char*)d_ws;
    const size_t NR = (size_t)NQP_ * 256;
    float* b_pos = (float*)ws;                                   // NR f32
    unsigned short* b_srcbf = (unsigned short*)(ws + NR * 4);    // NR bf16
    unsigned short* b_qbf   = (unsigned short*)(ws + NR * 6);    // NR bf16
    unsigned short* b_wt    = (unsigned short*)(ws + NR * 8);    // 2*786432 bf16
    char* R = ws + NR * 8 + (size_t)2 * 786432 * 2;
    unsigned short* b_valbf = (unsigned short*)(R);              // NR bf16   [R..R+2NR)
    unsigned short* b_oabf  = (unsigned short*)(R + NR * 2);     // NQP*512 bf16 [R+2NR..R+6NR)
    unsigned short* b_aggbf = (unsigned short*)(R + NR * 10);    // NR bf16  [R+10NR..R+12NR)
    unsigned short* b_tmpbf = (unsigned short*)(R);              // NR bf16 [R..R+2NR) (valbf dead by then)
    unsigned short* b_ffhbf = (unsigned short*)(R + NR * 4);     // NQP*1024 bf16 [R+4NR..R+12NR)
    unsigned short* b_tmp2bf = (unsigned short*)(R);             // NR bf16 [R..R+2NR) — disjoint from ffhbf

    // ---- weight prep: one kernel, 12 transposes ----
    WPArgs wa;
    int start = 0;
    for (int l = 0; l < NL_; ++l) {
        unsigned short* wt = b_wt + (size_t)l * 786432;
        WPEnt ents[6] = {
            {W_val + (size_t)l * 65536,  wt + 0,      256, 256,  start},
            {W_off + (size_t)l * 98304,  wt + 65536,  256, 384,  start + 64},
            {W_att + (size_t)l * 32768,  wt + 163840, 256, 128,  start + 160},
            {W_out + (size_t)l * 65536,  wt + 196608, 256, 256,  start + 192},
            {W_ff1 + (size_t)l * 262144, wt + 262144, 256, 1024, start + 256},
            {W_ff2 + (size_t)l * 262144, wt + 524288, 1024, 256, start + 512},
        };
        for (int j = 0; j < 6; ++j) wa.e[l * 6 + j] = ents[j];
        start += 768;
    }
    k_wprep_all<<<dim3(1536), 256, 0, stream>>>(wa);

    FlatArgs fa;
    for (int i = 0; i < 4; ++i) {
        fa.s[i] = (const float*)d_in[2 * i];
        fa.p[i] = (const float*)d_in[2 * i + 1];
    }
    k_flatten<<<dim3(NQ_), 256, 0, stream>>>(fa, lemb, b_srcbf, b_pos, b_qbf);

    const int GR = NQP_ / 128;  // 293
    const int BIG = 1 << 30;
    for (int l = 0; l < NL_; ++l) {
        unsigned short* wt = b_wt + (size_t)l * 786432;
        int last = (l == NL_ - 1);
        k_gemm<256, 2><<<dim3(GR, 2), 256, 0, stream>>>(
            b_srcbf, wt + 0, bVal + l * 256, bVal + l * 256, BIG, nullptr, b_valbf, 256);
        k_gemm<256, 2><<<dim3(GR, 4), 256, 0, stream>>>(
            b_qbf, wt + 65536, bOff + l * 384, bAtt + l * 128, 384, nullptr, b_oabf, 512);
        k_sample<<<dim3(NQ_ / 2), 256, 0, stream>>>(b_oabf, b_valbf, b_aggbf);
        k_gemm<256, 2><<<dim3(GR, 2), 256, 0, stream>>>(
            b_aggbf, wt + 196608, bOut + l * 256, bOut + l * 256, BIG, nullptr, b_tmpbf, 256);
        k_add_ln<<<dim3(NQ_ / 4), 256, 0, stream>>>(b_srcbf, b_tmpbf, ln1g + l * 256,
                                                    ln1b + l * 256, b_srcbf, nullptr,
                                                    nullptr, nullptr);
        k_gemm<256, 1><<<dim3(GR, 8), 256, 0, stream>>>(
            b_srcbf, wt + 262144, bFf1 + l * 1024, bFf1 + l * 1024, BIG, nullptr, b_ffhbf, 1024);
        k_gemm<1024, 2><<<dim3(GR, 2), 256, 0, stream>>>(
            b_ffhbf, wt + 524288, bFf2 + l * 256, bFf2 + l * 256, BIG, nullptr, b_tmp2bf, 256);
        k_add_ln<<<dim3(NQ_ / 4), 256, 0, stream>>>(b_srcbf, b_tmp2bf, ln2g + l * 256,
                                                    ln2b + l * 256,
                                                    last ? nullptr : b_srcbf,
                                                    last ? (float*)d_out : nullptr,
                                                    last ? nullptr : b_pos,
                                                    last ? nullptr : b_qbf);
    }
}

// Round 19
// 675.910 us; speedup vs baseline: 1.1856x; 1.0368x over previous
//
#include <hip/hip_runtime.h>
#include <hip/hip_bf16.h>
#include <math.h>

typedef __attribute__((ext_vector_type(4))) float f32x4;
typedef __attribute__((ext_vector_type(8))) short bf16x8;

static constexpr int B_   = 2;
static constexpr int DM_  = 256;
static constexpr int NL_  = 2;
static constexpr int LEN_ = 18720;
static constexpr int NQ_  = 37440;           // B*LEN
static constexpr int NQP_ = 37504;           // 128*293

__device__ __forceinline__ unsigned short f2bf(float x) {
    __hip_bfloat16 h = __float2bfloat16(x);
    return *reinterpret_cast<unsigned short*>(&h);
}
__device__ __forceinline__ float bf2f(unsigned short u) {
    unsigned int v = ((unsigned int)u) << 16;
    return __uint_as_float(v);
}

// ============ flatten: all levels; emits srcbf, pos, qbf (bf16 residual stream) ===
struct FlatArgs { const float* s[4]; const float* p[4]; };
__global__ __launch_bounds__(256) void k_flatten(FlatArgs a, const float* __restrict__ lemb,
                                                 unsigned short* __restrict__ srcbf,
                                                 float* __restrict__ pos,
                                                 unsigned short* __restrict__ qbf) {
    int t = blockIdx.x, c = threadIdx.x;
    int l, rel;
    if (t < 32768)      { l = 0; rel = t; }
    else if (t < 36864) { l = 1; rel = t - 32768; }
    else if (t < 37376) { l = 2; rel = t - 36864; }
    else                { l = 3; rel = t - 37376; }
    const int SH[4] = {14, 11, 8, 5};            // log2(S)
    const int OFF[4] = {0, 16384, 18432, 18688};
    int S = 1 << SH[l];
    int b = rel >> SH[l], s = rel & (S - 1);
    float sv = a.s[l][(size_t)(b * DM_ + c) * S + s];
    float pv = a.p[l][(size_t)(b * DM_ + c) * S + s] + lemb[l * DM_ + c];
    size_t row = (size_t)b * LEN_ + OFF[l] + s;
    srcbf[row * DM_ + c] = f2bf(sv);
    pos[row * DM_ + c] = pv;
    qbf[row * DM_ + c] = f2bf(sv + pv);
}

// ============ weight prep: all transposes in one kernel ============
struct WPEnt { const float* s; unsigned short* d; int K, N, start; };
struct WPArgs { WPEnt e[12]; };
__global__ __launch_bounds__(256) void k_wprep_all(WPArgs a) {
    __shared__ float t[32][33];
    int bidx = blockIdx.x;
    int i = 0;
#pragma unroll
    for (int j = 1; j < 12; ++j) if (bidx >= a.e[j].start) i = j;
    const float* W = a.e[i].s;
    unsigned short* Wt = a.e[i].d;
    int K = a.e[i].K, N = a.e[i].N;
    int ti = bidx - a.e[i].start;
    int tilesX = N >> 5;
    int bx = ti % tilesX, by = ti / tilesX;
    int n0 = bx * 32, k0 = by * 32;
    int tx = threadIdx.x & 31, ty = threadIdx.x >> 5;
#pragma unroll
    for (int q = 0; q < 4; ++q)
        t[ty + q * 8][tx] = W[(size_t)(k0 + ty + q * 8) * N + n0 + tx];
    __syncthreads();
#pragma unroll
    for (int q = 0; q < 4; ++q)
        Wt[(size_t)(n0 + ty + q * 8) * K + k0 + tx] = f2bf(t[tx][ty + q * 8]);
}

// ============ bf16 MFMA GEMM, 128x128 tile, BK=32 ============
// MODE 0: C fp32.  MODE 1: relu -> Cbf bf16.  MODE 2: Cbf bf16.
template<int K, int MODE>
__global__ __launch_bounds__(256) void k_gemm(const unsigned short* __restrict__ A,
                                              const unsigned short* __restrict__ Bt,
                                              const float* __restrict__ bias,
                                              const float* __restrict__ bias2,
                                              int nsplit,
                                              float* __restrict__ C,
                                              unsigned short* __restrict__ Cbf,
                                              int N) {
    __shared__ unsigned short As[128 * 32];
    __shared__ unsigned short Bs[128 * 32];
    int tid = threadIdx.x;
    int w = tid >> 6, lane = tid & 63;
    int wr = w >> 1, wc = w & 1;
    int row0 = blockIdx.x * 128, col0 = blockIdx.y * 128;

    const unsigned short* gA = A + (size_t)(row0 + w * 32 + (lane >> 2)) * K + (lane & 3) * 8;
    const unsigned short* gB = Bt + (size_t)(col0 + w * 32 + (lane >> 2)) * K + (lane & 3) * 8;
    char* lA0 = (char*)As + w * 2048;
    char* lB0 = (char*)Bs + w * 2048;

    f32x4 acc[4][4];
#pragma unroll
    for (int m = 0; m < 4; ++m)
#pragma unroll
        for (int n = 0; n < 4; ++n) acc[m][n] = (f32x4){0.f, 0.f, 0.f, 0.f};

    int lr = lane & 15, lk = (lane >> 4) * 8;
    const unsigned short* pA = &As[(wr * 64 + lr) * 32 + lk];
    const unsigned short* pB = &Bs[(wc * 64 + lr) * 32 + lk];

    for (int kt = 0; kt < K; kt += 32) {
        __builtin_amdgcn_global_load_lds((const __attribute__((address_space(1))) void*)gA,
                                         (__attribute__((address_space(3))) void*)lA0, 16, 0, 0);
        __builtin_amdgcn_global_load_lds((const __attribute__((address_space(1))) void*)(gA + (size_t)16 * K),
                                         (__attribute__((address_space(3))) void*)(lA0 + 1024), 16, 0, 0);
        __builtin_amdgcn_global_load_lds((const __attribute__((address_space(1))) void*)gB,
                                         (__attribute__((address_space(3))) void*)lB0, 16, 0, 0);
        __builtin_amdgcn_global_load_lds((const __attribute__((address_space(1))) void*)(gB + (size_t)16 * K),
                                         (__attribute__((address_space(3))) void*)(lB0 + 1024), 16, 0, 0);
        gA += 32; gB += 32;
        __syncthreads();
        bf16x8 a[4], b[4];
#pragma unroll
        for (int m = 0; m < 4; ++m) a[m] = *(const bf16x8*)(pA + m * 16 * 32);
#pragma unroll
        for (int n = 0; n < 4; ++n) b[n] = *(const bf16x8*)(pB + n * 16 * 32);
#pragma unroll
        for (int m = 0; m < 4; ++m)
#pragma unroll
            for (int n = 0; n < 4; ++n)
                acc[m][n] = __builtin_amdgcn_mfma_f32_16x16x32_bf16(a[m], b[n], acc[m][n], 0, 0, 0);
        __syncthreads();
    }

    int fr = (lane >> 4) * 4, fc = lane & 15;
#pragma unroll
    for (int m = 0; m < 4; ++m) {
#pragma unroll
        for (int n = 0; n < 4; ++n) {
            int cc = col0 + wc * 64 + n * 16 + fc;
            float bv = (cc < nsplit) ? bias[cc] : bias2[cc - nsplit];
#pragma unroll
            for (int i = 0; i < 4; ++i) {
                int cr = row0 + wr * 64 + m * 16 + fr + i;
                float v = acc[m][n][i] + bv;
                if (MODE == 1) {
                    Cbf[(size_t)cr * N + cc] = f2bf(fmaxf(v, 0.f));
                } else if (MODE == 2) {
                    Cbf[(size_t)cr * N + cc] = f2bf(v);
                } else {
                    C[(size_t)cr * N + cc] = v;
                }
            }
        }
    }
}

// ============ fused softmax + trilinear sampling (v7) ============
// oa: [row][512] bf16 (0..383 offsets, 384..511 logits); value bf16.
// grid = NQ/2; block handles rows {r0, r0+1} of one XCD chunk.
// v7: pow2-exact reciprocal multiplies (no fp div), packed float2 LDS.
__global__ __launch_bounds__(256) void k_sample(const unsigned short* __restrict__ oa,
                                                const unsigned short* __restrict__ vbf,
                                                unsigned short* __restrict__ aggbf) {
    int bid = blockIdx.x;
    int r0 = (bid & 7) * (NQ_ / 8) + (bid >> 3) * 2;   // XCD-chunked pair
    __shared__ float2 swi[2][8][128];                   // (.x = weight, .y = idx bits)
    int tid = threadIdx.x;
    const int dD[4] = {16, 8, 4, 2}, dH[4] = {32, 16, 8, 4}, dW[4] = {32, 16, 8, 4};
    const float iD[4] = {1.f/16, 1.f/8, 1.f/4, 1.f/2};
    const float iH[4] = {1.f/32, 1.f/16, 1.f/8, 1.f/4};
    const int loff[4] = {0, 16384, 18432, 18688};

    // phase 1: all 256 threads; rr = tid>>7 selects row of the pair
    {
        int rr = tid >> 7, t = tid & 127;
        int row = r0 + rr;
        int b = row / LEN_, qi = row - b * LEN_;
        int lq, s;
        if (qi < 16384)      { lq = 0; s = qi; }
        else if (qi < 18432) { lq = 1; s = qi - 16384; }
        else if (qi < 18688) { lq = 2; s = qi - 18432; }
        else                 { lq = 3; s = qi - 18688; }
        int Hq = dH[lq], Wq = dW[lq];
        int zq = s / (Hq * Wq);
        int rm = s - zq * (Hq * Wq);
        int yq = rm / Wq, xq = rm - (rm / Wq) * Wq;
        // exact pow2 reciprocals: same values as the /Dq form
        float ref0 = (zq + 0.5f) * iD[lq];   // z-ref (paired with W_ per torch quirk)
        float ref1 = (yq + 0.5f) * iH[lq];
        float ref2 = (xq + 0.5f) * iH[lq];   // Wq == Hq tables

        int m = t >> 4, l = (t >> 2) & 3;
        float e = bf2f(oa[(size_t)row * 512 + 384 + t]);
        float mx = e;
#pragma unroll
        for (int o = 1; o < 16; o <<= 1) mx = fmaxf(mx, __shfl_xor(mx, o, 16));
        float ex = expf(e - mx);
        float sm = ex;
#pragma unroll
        for (int o = 1; o < 16; o <<= 1) sm += __shfl_xor(sm, o, 16);
        float aw = ex / sm;

        const int D_ = dD[l], H_ = dH[l], W_ = dW[l];
        float o0 = bf2f(oa[(size_t)row * 512 + t * 3 + 0]);
        float o1 = bf2f(oa[(size_t)row * 512 + t * 3 + 1]);
        float o2 = bf2f(oa[(size_t)row * 512 + t * 3 + 2]);
        // (ref + o/W)*W - 0.5  ==  ref*W + o - 0.5   (o/W exact for pow2 W)
        float x = ref0 * W_ + o0 - 0.5f;
        float y = ref1 * H_ + o1 - 0.5f;
        float z = ref2 * D_ + o2 - 0.5f;
        float xf = floorf(x), yf = floorf(y), zf = floorf(z);
        float fx = x - xf, fy = y - yf, fz = z - zf;
        int x0 = (int)xf, y0 = (int)yf, z0 = (int)zf;
        int vbase = (b * LEN_ + loff[l]) * DM_ + m * 32;
#pragma unroll
        for (int dz = 0; dz < 2; ++dz)
#pragma unroll
            for (int dy = 0; dy < 2; ++dy)
#pragma unroll
                for (int dx = 0; dx < 2; ++dx) {
                    int xi = x0 + dx, yi = y0 + dy, zi = z0 + dz;
                    float wgt = (dx ? fx : 1.f - fx) * (dy ? fy : 1.f - fy) * (dz ? fz : 1.f - fz);
                    bool valid = (xi >= 0) & (xi < W_) & (yi >= 0) & (yi < H_) &
                                 (zi >= 0) & (zi < D_);
                    int xc = min(max(xi, 0), W_ - 1);
                    int yc = min(max(yi, 0), H_ - 1);
                    int zc = min(max(zi, 0), D_ - 1);
                    int idx = (zc * H_ + yc) * W_ + xc;
                    int cr = (dz << 2) | (dy << 1) | dx;
                    float2 pr;
                    pr.x = valid ? aw * wgt : 0.f;
                    pr.y = __int_as_float(vbase + idx * DM_);
                    swi[rr][cr][t] = pr;
                }
    }
    __syncthreads();

    // phase 2: both rows, all 256 threads each
    int m = tid >> 5;
    int lane5 = tid & 31;
    int sub = lane5 >> 2, cg = lane5 & 3;
#pragma unroll
    for (int rr = 0; rr < 2; ++rr) {
        int row = r0 + rr;
        float acc[8];
#pragma unroll
        for (int i = 0; i < 8; ++i) acc[i] = 0.f;
#pragma unroll
        for (int t = 0; t < 16; ++t) {
            int pair = sub * 16 + t;           // 128 (point,corner) pairs
            int tq = pair >> 3, cr = pair & 7;
            float2 pw = swi[rr][cr][m * 16 + tq];
            float wq = pw.x;
            int ofs = __float_as_int(pw.y);
            uint4 v = *(const uint4*)&vbf[ofs + cg * 8];
            acc[0] = fmaf(wq, __uint_as_float(v.x << 16), acc[0]);
            acc[1] = fmaf(wq, __uint_as_float(v.x & 0xffff0000u), acc[1]);
            acc[2] = fmaf(wq, __uint_as_float(v.y << 16), acc[2]);
            acc[3] = fmaf(wq, __uint_as_float(v.y & 0xffff0000u), acc[3]);
            acc[4] = fmaf(wq, __uint_as_float(v.z << 16), acc[4]);
            acc[5] = fmaf(wq, __uint_as_float(v.z & 0xffff0000u), acc[5]);
            acc[6] = fmaf(wq, __uint_as_float(v.w << 16), acc[6]);
            acc[7] = fmaf(wq, __uint_as_float(v.w & 0xffff0000u), acc[7]);
        }
#pragma unroll
        for (int i = 0; i < 8; ++i) {
            acc[i] += __shfl_xor(acc[i], 4, 64);
            acc[i] += __shfl_xor(acc[i], 8, 64);
            acc[i] += __shfl_xor(acc[i], 16, 64);
        }
        if (sub == 0) {
            uint4 o;
            o.x = ((unsigned)f2bf(acc[1]) << 16) | f2bf(acc[0]);
            o.y = ((unsigned)f2bf(acc[3]) << 16) | f2bf(acc[2]);
            o.z = ((unsigned)f2bf(acc[5]) << 16) | f2bf(acc[4]);
            o.w = ((unsigned)f2bf(acc[7]) << 16) | f2bf(acc[6]);
            *(uint4*)&aggbf[(size_t)row * DM_ + m * 32 + cg * 8] = o;
        }
    }
}

// ============ fused residual-add + LayerNorm; all-bf16 residual stream =======
__global__ __launch_bounds__(256) void k_add_ln(const unsigned short* __restrict__ X,
                                                const unsigned short* __restrict__ Rr,
                                                const float* __restrict__ g,
                                                const float* __restrict__ bb,
                                                unsigned short* __restrict__ Obf,
                                                float* __restrict__ Ofp,
                                                const float* __restrict__ pos,
                                                unsigned short* __restrict__ qbf) {
    int wid = threadIdx.x >> 6, lane = threadIdx.x & 63;
    size_t row = (size_t)blockIdx.x * 4 + wid;
    ushort4 x4 = ((const ushort4*)&X[row * DM_])[lane];
    ushort4 r4 = ((const ushort4*)&Rr[row * DM_])[lane];
    float v[4] = {bf2f(x4.x) + bf2f(r4.x), bf2f(x4.y) + bf2f(r4.y),
                  bf2f(x4.z) + bf2f(r4.z), bf2f(x4.w) + bf2f(r4.w)};
    float sm = v[0] + v[1] + v[2] + v[3];
#pragma unroll
    for (int o = 32; o; o >>= 1) sm += __shfl_xor(sm, o, 64);
    float mu = sm * (1.f / 256.f);
    float q = 0.f;
#pragma unroll
    for (int i = 0; i < 4; ++i) { float d = v[i] - mu; q += d * d; }
#pragma unroll
    for (int o = 32; o; o >>= 1) q += __shfl_xor(q, o, 64);
    float inv = rsqrtf(q * (1.f / 256.f) + 1e-5f);
    int c0 = lane * 4;
    float4 gv = *(const float4*)&g[c0];
    float4 bv = *(const float4*)&bb[c0];
    float4 o4;
    o4.x = (v[0] - mu) * inv * gv.x + bv.x;
    o4.y = (v[1] - mu) * inv * gv.y + bv.y;
    o4.z = (v[2] - mu) * inv * gv.z + bv.z;
    o4.w = (v[3] - mu) * inv * gv.w + bv.w;
    if (Obf) {
        ushort4 ob;
        ob.x = f2bf(o4.x); ob.y = f2bf(o4.y); ob.z = f2bf(o4.z); ob.w = f2bf(o4.w);
        ((ushort4*)&Obf[row * DM_])[lane] = ob;
    }
    if (Ofp) ((float4*)&Ofp[row * DM_])[lane] = o4;
    if (qbf) {
        float4 pv = ((const float4*)&pos[row * DM_])[lane];
        ushort4 qb;
        qb.x = f2bf(o4.x + pv.x); qb.y = f2bf(o4.y + pv.y);
        qb.z = f2bf(o4.z + pv.z); qb.w = f2bf(o4.w + pv.w);
        ((ushort4*)&qbf[row * DM_])[lane] = qb;
    }
}

extern "C" void kernel_launch(void* const* d_in, const int* in_sizes, int n_in,
                              void* d_out, int out_size, void* d_ws, size_t ws_size,
                              hipStream_t stream) {
    const float* lemb  = (const float*)d_in[8];
    const float* W_off = (const float*)d_in[9];
    const float* bOff  = (const float*)d_in[10];
    const float* W_att = (const float*)d_in[11];
    const float* bAtt  = (const float*)d_in[12];
    const float* W_val = (const float*)d_in[13];
    const float* bVal  = (const float*)d_in[14];
    const float* W_out = (const float*)d_in[15];
    const float* bOut  = (const float*)d_in[16];
    const float* ln1g  = (const float*)d_in[17];
    const float* ln1b  = (const float*)d_in[18];
    const float* W_ff1 = (const float*)d_in[19];
    const float* bFf1  = (const float*)d_in[20];
    const float* W_ff2 = (const float*)d_in[21];
    const float* bFf2  = (const float*)d_in[22];
    const float* ln2g  = (const float*)d_in[23];
    const float* ln2b  = (const float*)d_in[24];

    // ---- workspace layout (byte offsets) ----
    char* ws = (char*)d_ws;
    const size_t NR = (size_t)NQP_ * 256;
    float* b_pos = (float*)ws;                                   // NR f32
    unsigned short* b_srcbf = (unsigned short*)(ws + NR * 4);    // NR bf16
    unsigned short* b_qbf   = (unsigned short*)(ws + NR * 6);    // NR bf16
    unsigned short* b_wt    = (unsigned short*)(ws + NR * 8);    // 2*786432 bf16
    char* R = ws + NR * 8 + (size_t)2 * 786432 * 2;
    unsigned short* b_valbf = (unsigned short*)(R);              // NR bf16   [R..R+2NR)
    unsigned short* b_oabf  = (unsigned short*)(R + NR * 2);     // NQP*512 bf16 [R+2NR..R+6NR)
    unsigned short* b_aggbf = (unsigned short*)(R + NR * 10);    // NR bf16  [R+10NR..R+12NR)
    unsigned short* b_tmpbf = (unsigned short*)(R);              // NR bf16 [R..R+2NR) (valbf dead by then)
    unsigned short* b_ffhbf = (unsigned short*)(R + NR * 4);     // NQP*1024 bf16 [R+4NR..R+12NR)
    unsigned short* b_tmp2bf = (unsigned short*)(R);             // NR bf16 [R..R+2NR) — disjoint from ffhbf

    // ---- weight prep: one kernel, 12 transposes ----
    WPArgs wa;
    int start = 0;
    for (int l = 0; l < NL_; ++l) {
        unsigned short* wt = b_wt + (size_t)l * 786432;
        WPEnt ents[6] = {
            {W_val + (size_t)l * 65536,  wt + 0,      256, 256,  start},
            {W_off + (size_t)l * 98304,  wt + 65536,  256, 384,  start + 64},
            {W_att + (size_t)l * 32768,  wt + 163840, 256, 128,  start + 160},
            {W_out + (size_t)l * 65536,  wt + 196608, 256, 256,  start + 192},
            {W_ff1 + (size_t)l * 262144, wt + 262144, 256, 1024, start + 256},
            {W_ff2 + (size_t)l * 262144, wt + 524288, 1024, 256, start + 512},
        };
        for (int j = 0; j < 6; ++j) wa.e[l * 6 + j] = ents[j];
        start += 768;
    }
    k_wprep_all<<<dim3(1536), 256, 0, stream>>>(wa);

    FlatArgs fa;
    for (int i = 0; i < 4; ++i) {
        fa.s[i] = (const float*)d_in[2 * i];
        fa.p[i] = (const float*)d_in[2 * i + 1];
    }
    k_flatten<<<dim3(NQ_), 256, 0, stream>>>(fa, lemb, b_srcbf, b_pos, b_qbf);

    const int GR = NQP_ / 128;  // 293
    const int BIG = 1 << 30;
    for (int l = 0; l < NL_; ++l) {
        unsigned short* wt = b_wt + (size_t)l * 786432;
        int last = (l == NL_ - 1);
        k_gemm<256, 2><<<dim3(GR, 2), 256, 0, stream>>>(
            b_srcbf, wt + 0, bVal + l * 256, bVal + l * 256, BIG, nullptr, b_valbf, 256);
        k_gemm<256, 2><<<dim3(GR, 4), 256, 0, stream>>>(
            b_qbf, wt + 65536, bOff + l * 384, bAtt + l * 128, 384, nullptr, b_oabf, 512);
        k_sample<<<dim3(NQ_ / 2), 256, 0, stream>>>(b_oabf, b_valbf, b_aggbf);
        k_gemm<256, 2><<<dim3(GR, 2), 256, 0, stream>>>(
            b_aggbf, wt + 196608, bOut + l * 256, bOut + l * 256, BIG, nullptr, b_tmpbf, 256);
        k_add_ln<<<dim3(NQ_ / 4), 256, 0, stream>>>(b_srcbf, b_tmpbf, ln1g + l * 256,
                                                    ln1b + l * 256, b_srcbf, nullptr,
                                                    nullptr, nullptr);
        k_gemm<256, 1><<<dim3(GR, 8), 256, 0, stream>>>(
            b_srcbf, wt + 262144, bFf1 + l * 1024, bFf1 + l * 1024, BIG, nullptr, b_ffhbf, 1024);
        k_gemm<1024, 2><<<dim3(GR, 2), 256, 0, stream>>>(
            b_ffhbf, wt + 524288, bFf2 + l * 256, bFf2 + l * 256, BIG, nullptr, b_tmp2bf, 256);
        k_add_ln<<<dim3(NQ_ / 4), 256, 0, stream>>>(b_srcbf, b_tmp2bf, ln2g + l * 256,
                                                    ln2b + l * 256,
                                                    last ? nullptr : b_srcbf,
                                                    last ? (float*)d_out : nullptr,
                                                    last ? nullptr : b_pos,
                                                    last ? nullptr : b_qbf);
    }
}